// Round 19
// baseline (189.609 us; speedup 1.0000x reference)
//
#include <hip/hip_runtime.h>
#include <math.h>

// Problem constants (B=4, L=2048, C=1024, H=16, D=64)
#define BB 4
#define LL 2048
#define CC 1024
#define HH 16
#define DD 64
#define MM (BB * LL) // 8192 rows

typedef float f32x4 __attribute__((ext_vector_type(4)));
typedef short short8 __attribute__((ext_vector_type(8))); // 8 bf16 (4 VGPRs)
typedef unsigned short ushort_t;
typedef unsigned long long u64_t;

#define MFMA_BF16(A, B, C) __builtin_amdgcn_mfma_f32_16x16x32_bf16(A, B, C, 0, 0, 0)

// q pre-scale: 1/sqrt(D) * log2(e), so softmax runs in exp2 domain
#define QSCALE 0.180336880f

__device__ __forceinline__ unsigned short f2bf(float x) {
    unsigned int u = __float_as_uint(x);
    u += 0x7fffu + ((u >> 16) & 1u); // RTN-even
    return (unsigned short)(u >> 16);
}

// pack two positive f32 into (bf16(b)<<16)|bf16(a), round-half-up via +0x8000
__device__ __forceinline__ unsigned pack_bf2(float a, float b) {
#if __has_builtin(__builtin_amdgcn_perm)
    return __builtin_amdgcn_perm(__float_as_uint(b) + 0x8000u,
                                 __float_as_uint(a) + 0x8000u, 0x07060302u);
#else
    return ((__float_as_uint(b) + 0x8000u) & 0xFFFF0000u) |
           ((__float_as_uint(a) + 0x8000u) >> 16);
#endif
}

// raw v_exp_f32 (domain here has no denormals; skip libm fixup)
__device__ __forceinline__ float fast_exp2(float x) {
#if __has_builtin(__builtin_amdgcn_exp2f)
    return __builtin_amdgcn_exp2f(x);
#else
    return exp2f(x);
#endif
}

// async global -> LDS DMA, 16 B per lane; LDS dest = wave-uniform base + lane*16
__device__ __forceinline__ void gload_lds16(const ushort_t* g, ushort_t* l) {
    __builtin_amdgcn_global_load_lds(
        (const __attribute__((address_space(1))) void*)g,
        (__attribute__((address_space(3))) void*)l,
        16, 0, 0);
}

// ---------------------------------------------------------------------------
// Fused prep: one launch.
//   blocks [0, 4096):        x f32 -> bf16 xh
//   blocks [4096, 4864):     Wqkv transpose+round -> wqh [3C][C]
//   blocks [4864, 5120):     Wout transpose+round -> woh [C][C]
// ---------------------------------------------------------------------------
__global__ __launch_bounds__(256)
void prep_all(const float* __restrict__ x, ushort_t* __restrict__ xh,
              const float* __restrict__ Wq, ushort_t* __restrict__ Tq,
              const float* __restrict__ Wo, ushort_t* __restrict__ To)
{
    __shared__ float sT[64][65];
    int bid = blockIdx.x;
    const int tid = threadIdx.x;

    if (bid < 4096) { // x rounding: 8 f32 per thread
        const int i = (bid * 256 + tid) * 8;
        f32x4 a = *(const f32x4*)(x + i);
        f32x4 b = *(const f32x4*)(x + i + 4);
        short8 h;
#pragma unroll
        for (int j = 0; j < 4; ++j) {
            h[j]     = (short)f2bf(a[j]);
            h[4 + j] = (short)f2bf(b[j]);
        }
        *(short8*)(xh + i) = h;
        return;
    }
    bid -= 4096;

    const float* W;
    ushort_t* T;
    int N, bx, by;
    if (bid < 768) { W = Wq; T = Tq; N = 3 * CC; bx = bid % 48; by = bid / 48; }
    else { bid -= 768; W = Wo; T = To; N = CC; bx = bid % 16; by = bid / 16; }

    const int K = CC;
    const int k0 = by * 64, n0 = bx * 64;
    const int r = tid >> 2, c0 = (tid & 3) * 16;

    const float* wp = W + (size_t)(k0 + r) * N + n0 + c0;
#pragma unroll
    for (int u = 0; u < 4; ++u) {
        f32x4 v = *(const f32x4*)(wp + 4 * u);
        sT[r][c0 + 4 * u + 0] = v[0];
        sT[r][c0 + 4 * u + 1] = v[1];
        sT[r][c0 + 4 * u + 2] = v[2];
        sT[r][c0 + 4 * u + 3] = v[3];
    }
    __syncthreads();

    const int nn = tid >> 2, kk0 = (tid & 3) * 16;
    short8 h0, h1;
#pragma unroll
    for (int u = 0; u < 8; ++u) {
        h0[u] = (short)f2bf(sT[kk0 + u][nn]);
        h1[u] = (short)f2bf(sT[kk0 + 8 + u][nn]);
    }
    ushort_t* oh = T + (size_t)(n0 + nn) * K + k0 + kk0;
    *(short8*)oh = h0; *(short8*)(oh + 8) = h1;
}

// ---------------------------------------------------------------------------
// Fused QKV GEMM, single-term bf16, next-K-tile register prefetch.
// Epilogue: rmsnorm q -> bf16 Qbh (xQSCALE), rmsnorm k -> bf16 Kh
// [b][h][l][d], v -> bf16 Vth transposed [b][h][d][l].
// ---------------------------------------------------------------------------
__global__ __launch_bounds__(256, 3)
void gemm_qkv(const ushort_t* __restrict__ Agh,
              const ushort_t* __restrict__ Bh,
              const float* __restrict__ bias,
              const float* __restrict__ gq, const float* __restrict__ gk,
              ushort_t* __restrict__ Qbh,
              ushort_t* __restrict__ Kh,
              ushort_t* __restrict__ Vth)
{
    __shared__ ushort_t smem[16384]; // 32 KB
    ushort_t* sAh = smem;
    ushort_t* sBh = smem + 8192;

    const int K = CC, lda = CC, nbx = (3 * CC) / 128; // 24

    const int nwg = gridDim.x;
    const int cpx = nwg >> 3;
    const int id  = blockIdx.x;
    const int swz = (id & 7) * cpx + (id >> 3);
    const int bx = swz % nbx, by = swz / nbx;
    const int m0 = by * 128, n0 = bx * 128;

    const int tid  = threadIdx.x;
    const int lane = tid & 63;
    const int wv   = tid >> 6;
    const int l4   = lane >> 4, l16 = lane & 15;
    const int wm   = wv >> 1,  wn  = wv & 1;

    const int r0  = tid >> 2;
    const int c0  = (tid & 3) * 16;
    const int ch0 = c0 >> 3;

    f32x4 acc[4][4];
#pragma unroll
    for (int i = 0; i < 4; ++i)
#pragma unroll
        for (int j = 0; j < 4; ++j) acc[i][j] = 0.f;

    short8 stgA[4], stgB[4];
#pragma unroll
    for (int it = 0; it < 2; ++it) {
        const ushort_t* ahp = Agh + (size_t)(m0 + r0 + 64 * it) * lda + c0;
        stgA[2 * it]     = *(const short8*)(ahp);
        stgA[2 * it + 1] = *(const short8*)(ahp + 8);
        const ushort_t* bhp = Bh + (size_t)(n0 + r0 + 64 * it) * K + c0;
        stgB[2 * it]     = *(const short8*)(bhp);
        stgB[2 * it + 1] = *(const short8*)(bhp + 8);
    }

    for (int kt = 0; kt < K; kt += 64) {
        __syncthreads();
#pragma unroll
        for (int it = 0; it < 2; ++it) {
            const int row  = r0 + 64 * it;
            const int sA   = row & 7;
            const int base = row * 64;
            const int cA = ((ch0) ^ sA) * 8, cB = ((ch0 + 1) ^ sA) * 8;
            *(short8*)&sAh[base + cA] = stgA[2 * it];
            *(short8*)&sAh[base + cB] = stgA[2 * it + 1];
            *(short8*)&sBh[base + cA] = stgB[2 * it];
            *(short8*)&sBh[base + cB] = stgB[2 * it + 1];
        }
        __syncthreads();

        if (kt + 64 < K) { // prefetch next K-tile (overlaps MFMA below)
#pragma unroll
            for (int it = 0; it < 2; ++it) {
                const ushort_t* ahp = Agh + (size_t)(m0 + r0 + 64 * it) * lda + kt + 64 + c0;
                stgA[2 * it]     = *(const short8*)(ahp);
                stgA[2 * it + 1] = *(const short8*)(ahp + 8);
                const ushort_t* bhp = Bh + (size_t)(n0 + r0 + 64 * it) * K + kt + 64 + c0;
                stgB[2 * it]     = *(const short8*)(bhp);
                stgB[2 * it + 1] = *(const short8*)(bhp + 8);
            }
        }

#pragma unroll
        for (int ks = 0; ks < 2; ++ks) {
            const int chf = (((ks << 2) | l4) ^ (l16 & 7)) * 8;
            short8 fbh[4];
#pragma unroll
            for (int j = 0; j < 4; ++j) {
                const int idx = (64 * wn + 16 * j + l16) * 64 + chf;
                fbh[j] = *(const short8*)&sBh[idx];
            }
#pragma unroll
            for (int i = 0; i < 4; ++i) {
                const int idx = (64 * wm + 16 * i + l16) * 64 + chf;
                short8 fah = *(const short8*)&sAh[idx];
#pragma unroll
                for (int j = 0; j < 4; ++j)
                    acc[i][j] = MFMA_BF16(fah, fbh[j], acc[i][j]);
            }
        }
    }

    // ---- epilogue -------------------------------------------------------
    const int region = n0 >> 10; // 0=q, 1=k, 2=v
    float bv[4];
#pragma unroll
    for (int j = 0; j < 4; ++j) bv[j] = bias[n0 + 64 * wn + 16 * j + l16];
#pragma unroll
    for (int i = 0; i < 4; ++i)
#pragma unroll
        for (int j = 0; j < 4; ++j)
#pragma unroll
            for (int r = 0; r < 4; ++r) acc[i][j][r] += bv[j];

    const int b = m0 >> 11;

    if (region < 2) {
        const int hloc = ((n0 & 1023) >> 6) + wn;
        const float* g = (region == 0 ? gq : gk) + hloc * DD;
        float gv[4];
#pragma unroll
        for (int j = 0; j < 4; ++j) gv[j] = g[16 * j + l16];
#pragma unroll
        for (int i = 0; i < 4; ++i)
#pragma unroll
        for (int r = 0; r < 4; ++r) {
            float ss = 0.f;
#pragma unroll
            for (int j = 0; j < 4; ++j) ss += acc[i][j][r] * acc[i][j][r];
#pragma unroll
            for (int off = 1; off < 16; off <<= 1) ss += __shfl_xor(ss, off);
            const float s = 8.0f / fmaxf(sqrtf(ss), 1e-12f);
#pragma unroll
            for (int j = 0; j < 4; ++j) acc[i][j][r] *= s * gv[j];
        }

        if (region == 0) {
            // q: bf16, pre-scaled for exp2-domain softmax
#pragma unroll
            for (int i = 0; i < 4; ++i)
#pragma unroll
            for (int r = 0; r < 4; ++r) {
                const int row = m0 + 64 * wm + 16 * i + 4 * l4 + r;
                ushort_t* op = Qbh + (size_t)row * CC + n0 + 64 * wn + l16;
#pragma unroll
                for (int j = 0; j < 4; ++j)
                    op[16 * j] = f2bf(acc[i][j][r] * QSCALE);
            }
        } else {
            const int hk = ((n0 - 1024) >> 6) + wn;
#pragma unroll
            for (int i = 0; i < 4; ++i)
#pragma unroll
            for (int r = 0; r < 4; ++r) {
                const int l = (m0 & 2047) + 64 * wm + 16 * i + 4 * l4 + r;
                const size_t base = ((size_t)(b * HH + hk) * LL + l) * DD + l16;
#pragma unroll
                for (int j = 0; j < 4; ++j)
                    Kh[base + 16 * j] = f2bf(acc[i][j][r]);
            }
        }
    } else {
        // V: bf16 + 128x128 LDS transpose + vector store to [b][h][d][l]
        __syncthreads();
        ushort_t* vh = smem; // [128][128] = 32 KB exactly
#pragma unroll
        for (int i = 0; i < 4; ++i)
#pragma unroll
        for (int r = 0; r < 4; ++r) {
            const int lr = 64 * wm + 16 * i + 4 * l4 + r;
#pragma unroll
            for (int j = 0; j < 4; ++j) {
                const int c = 64 * wn + 16 * j + l16;
                vh[lr * 128 + c] = f2bf(acc[i][j][r]);
            }
        }
        __syncthreads();
        const int c    = tid & 127;
        const int half = tid >> 7;
        const int hv   = ((n0 - 2048) >> 6) + (c >> 6);
        const int d    = c & 63;
        ushort_t* oh = Vth + ((size_t)(b * HH + hv) * DD + d) * LL + (m0 & 2047) + half * 64;
#pragma unroll
        for (int u = 0; u < 8; ++u) {
            const int l0 = half * 64 + u * 8;
            short8 hv8;
#pragma unroll
            for (int e = 0; e < 8; ++e)
                hv8[e] = (short)vh[(l0 + e) * 128 + c];
            *(short8*)&oh[u * 8] = hv8;
        }
    }
}

// ---------------------------------------------------------------------------
// Output projection, single-term bf16 with register prefetch.
// ---------------------------------------------------------------------------
__global__ __launch_bounds__(256, 3)
void gemm_out1(const ushort_t* __restrict__ Ah,
               const ushort_t* __restrict__ Bh,
               const float* __restrict__ bias, float* __restrict__ Cg)
{
    __shared__ ushort_t sAh[8192];
    __shared__ ushort_t sBh[8192];

    const int K = CC, nbx = CC / 128; // 8

    const int nwg = gridDim.x;
    const int cpx = nwg >> 3;
    const int id  = blockIdx.x;
    const int sw  = (id & 7) * cpx + (id >> 3);
    const int bx = sw % nbx, by = sw / nbx;
    const int m0 = by * 128, n0 = bx * 128;

    const int tid  = threadIdx.x;
    const int lane = tid & 63;
    const int wv   = tid >> 6;
    const int l4   = lane >> 4, l16 = lane & 15;
    const int wm   = wv >> 1,  wn  = wv & 1;

    const int r0  = tid >> 2;
    const int c0  = (tid & 3) * 16;
    const int ch0 = c0 >> 3;

    f32x4 acc[4][4];
#pragma unroll
    for (int i = 0; i < 4; ++i)
#pragma unroll
        for (int j = 0; j < 4; ++j) acc[i][j] = 0.f;

    short8 stgA[4], stgB[4];
#pragma unroll
    for (int it = 0; it < 2; ++it) {
        const ushort_t* ahp = Ah + (size_t)(m0 + r0 + 64 * it) * CC + c0;
        stgA[2 * it]     = *(const short8*)(ahp);
        stgA[2 * it + 1] = *(const short8*)(ahp + 8);
        const ushort_t* bhp = Bh + (size_t)(n0 + r0 + 64 * it) * K + c0;
        stgB[2 * it]     = *(const short8*)(bhp);
        stgB[2 * it + 1] = *(const short8*)(bhp + 8);
    }

    for (int kt = 0; kt < K; kt += 64) {
        __syncthreads();
#pragma unroll
        for (int it = 0; it < 2; ++it) {
            const int row  = r0 + 64 * it;
            const int sA   = row & 7;
            const int base = row * 64;
            const int cA = ((ch0) ^ sA) * 8, cB = ((ch0 + 1) ^ sA) * 8;
            *(short8*)&sAh[base + cA] = stgA[2 * it];
            *(short8*)&sAh[base + cB] = stgA[2 * it + 1];
            *(short8*)&sBh[base + cA] = stgB[2 * it];
            *(short8*)&sBh[base + cB] = stgB[2 * it + 1];
        }
        __syncthreads();

        if (kt + 64 < K) { // prefetch next K-tile
#pragma unroll
            for (int it = 0; it < 2; ++it) {
                const ushort_t* ahp = Ah + (size_t)(m0 + r0 + 64 * it) * CC + kt + 64 + c0;
                stgA[2 * it]     = *(const short8*)(ahp);
                stgA[2 * it + 1] = *(const short8*)(ahp + 8);
                const ushort_t* bhp = Bh + (size_t)(n0 + r0 + 64 * it) * K + kt + 64 + c0;
                stgB[2 * it]     = *(const short8*)(bhp);
                stgB[2 * it + 1] = *(const short8*)(bhp + 8);
            }
        }

#pragma unroll
        for (int ks = 0; ks < 2; ++ks) {
            const int chf = (((ks << 2) | l4) ^ (l16 & 7)) * 8;
            short8 fbh[4];
#pragma unroll
            for (int j = 0; j < 4; ++j) {
                const int idx = (64 * wn + 16 * j + l16) * 64 + chf;
                fbh[j] = *(const short8*)&sBh[idx];
            }
#pragma unroll
            for (int i = 0; i < 4; ++i) {
                const int idx = (64 * wm + 16 * i + l16) * 64 + chf;
                short8 fah = *(const short8*)&sAh[idx];
#pragma unroll
                for (int j = 0; j < 4; ++j)
                    acc[i][j] = MFMA_BF16(fah, fbh[j], acc[i][j]);
            }
        }
    }

    float bv[4];
#pragma unroll
    for (int j = 0; j < 4; ++j) bv[j] = bias[n0 + 64 * wn + 16 * j + l16];
#pragma unroll
    for (int i = 0; i < 4; ++i)
#pragma unroll
    for (int r = 0; r < 4; ++r) {
        const int row = m0 + 64 * wm + 16 * i + 4 * l4 + r;
        float* cp = Cg + (size_t)row * CC + n0 + 64 * wn + l16;
#pragma unroll
        for (int j = 0; j < 4; ++j) cp[16 * j] = acc[i][j][r] + bv[j];
    }
}

// ---------------------------------------------------------------------------
// Flash attention v12: QF=4 + global_load_lds DMA staging with double-buffered
// K/V and ONE barrier per tile (T3 minimum 2-phase). LDS linear for the DMA;
// XOR swizzle preserved by pre-swizzling the per-lane GLOBAL source chunk
// (c ^ (row&7)), so the swizzled fragment reads are unchanged. Fixed-shift
// exp2 softmax, row-sum l via MFMA(P, ones).
// ---------------------------------------------------------------------------
__global__ __launch_bounds__(256, 2)
void flash12(const ushort_t* __restrict__ Qbh,
             const ushort_t* __restrict__ Kh,
             const ushort_t* __restrict__ Vth,
             ushort_t* __restrict__ Hb)
{
    __shared__ ushort_t sKh[2][4096];   // 16 KB (2 x 64x64 bf16)
    __shared__ ushort_t sVh[2][4096];   // 16 KB
    __shared__ ushort_t sP[4][64 * 68]; // 34 KB

    const int i    = blockIdx.x;          // 0..511
    const int xcd  = i & 7;
    const int slot = i >> 3;              // 0..63
    const int qt   = slot & 7;            // 8 q-tiles of 256 rows
    const int bh   = ((slot >> 3) << 3) | xcd;
    const int b    = bh >> 4, h = bh & 15;

    const int tid  = threadIdx.x;
    const int lane = tid & 63;
    const int wv   = tid >> 6;
    const int l4   = lane >> 4, l16 = lane & 15;

    // ---- Q fragments: 4 q-frags per wave (64 rows), pre-scaled bf16
    short8 qh[4][2];
    const int qr0 = qt * 256 + wv * 64;
#pragma unroll
    for (int qf = 0; qf < 4; ++qf)
#pragma unroll
    for (int sl = 0; sl < 2; ++sl)
        qh[qf][sl] = *(const short8*)(Qbh + (size_t)(b * LL + qr0 + qf * 16 + l16) * CC
                                      + h * DD + sl * 32 + l4 * 8);

    // bf16 1.0 vector for the MFMA row-sum
    short8 ones;
#pragma unroll
    for (int j = 0; j < 8; ++j) ones[j] = (short)0x3F80;

    f32x4 O[4][4];
    f32x4 acc_l[4];   // row-sum of P, layout q = 4*l4 + r (same as O rows)
#pragma unroll
    for (int qf = 0; qf < 4; ++qf) {
        acc_l[qf] = 0.f;
#pragma unroll
        for (int t = 0; t < 4; ++t) O[qf][t] = 0.f;
    }

    // ---- DMA staging: per wave 2 issues for K + 2 for V, 16 B/lane each.
    // LDS linear: wave w, issue j covers rows [w*16 + j*8, +8), lane>>3 = row
    // sub-index, lane&7 = LDS chunk c; source chunk = c ^ (row & 7).
    size_t koff[2], voff[2];
#pragma unroll
    for (int j = 0; j < 2; ++j) {
        const int row = wv * 16 + j * 8 + (lane >> 3);
        const int cs  = ((lane & 7) ^ (row & 7)) * 8;
        koff[j] = ((size_t)bh * LL + row) * DD + cs;  // + kt*64*DD per tile
        voff[j] = ((size_t)bh * DD + row) * LL + cs;  // + kt*64 per tile
    }

    int cur = 0;
    {
#pragma unroll
        for (int j = 0; j < 2; ++j) {
            gload_lds16(Kh  + koff[j], &sKh[0][wv * 1024 + j * 512]);
            gload_lds16(Vth + voff[j], &sVh[0][wv * 1024 + j * 512]);
        }
    }
    __syncthreads(); // drains vmcnt(0) (tile 0 loaded) + barrier

    for (int kt = 0; kt < LL / 64; ++kt) {
        if (kt + 1 < LL / 64) { // issue next tile into the other buffer
#pragma unroll
            for (int j = 0; j < 2; ++j) {
                gload_lds16(Kh  + koff[j] + (size_t)(kt + 1) * 64 * DD,
                            &sKh[cur ^ 1][wv * 1024 + j * 512]);
                gload_lds16(Vth + voff[j] + (size_t)(kt + 1) * 64,
                            &sVh[cur ^ 1][wv * 1024 + j * 512]);
            }
        }

        // ---- S^T = K Q : rows k (16t + 4*l4 + r), cols q (l16); log2 units
        f32x4 S[4][4];
#pragma unroll
        for (int qf = 0; qf < 4; ++qf)
#pragma unroll
        for (int t = 0; t < 4; ++t) S[qf][t] = 0.f;

        __builtin_amdgcn_s_setprio(1);
#pragma unroll
        for (int t = 0; t < 4; ++t) {
            const int row = 16 * t + l16;
            const int swr = row & 7;
#pragma unroll
            for (int sl = 0; sl < 2; ++sl) {
                const int idx = row * 64 + (((sl << 2) | l4) ^ swr) * 8;
                short8 kh8 = *(const short8*)&sKh[cur][idx];
#pragma unroll
                for (int qf = 0; qf < 4; ++qf)
                    S[qf][t] = MFMA_BF16(kh8, qh[qf][sl], S[qf][t]);
            }
        }
        __builtin_amdgcn_s_setprio(0);

        // ---- P = exp2(S) (fixed-shift softmax; constant cancels in O/l)
#pragma unroll
        for (int qf = 0; qf < 4; ++qf)
#pragma unroll
        for (int t = 0; t < 4; ++t)
#pragma unroll
            for (int r = 0; r < 4; ++r)
                S[qf][t][r] = fast_exp2(S[qf][t][r]);

        // ---- P -> per-wave LDS (bf16, half-up + v_perm pack), b64 writes
#pragma unroll
        for (int qf = 0; qf < 4; ++qf)
#pragma unroll
        for (int t = 0; t < 4; ++t) {
            unsigned lo = pack_bf2(S[qf][t][0], S[qf][t][1]);
            unsigned hi = pack_bf2(S[qf][t][2], S[qf][t][3]);
            const int widx = (qf * 16 + l16) * 68 + 16 * t + 4 * l4;
            *(u64_t*)&sP[wv][widx] = (u64_t)lo | ((u64_t)hi << 32);
        }
        asm volatile("s_waitcnt lgkmcnt(0)" ::: "memory");
        __builtin_amdgcn_sched_barrier(0);

        // ---- P A-fragments: row q = l16, k = sl*32 + 8*l4 + j
        short8 pa[4][2];
#pragma unroll
        for (int qf = 0; qf < 4; ++qf)
#pragma unroll
        for (int sl = 0; sl < 2; ++sl) {
            const int ridx = (qf * 16 + l16) * 68 + sl * 32 + 8 * l4;
            union { u64_t q[2]; short8 s8; } u;
            u.q[0] = *(const u64_t*)&sP[wv][ridx];
            u.q[1] = *(const u64_t*)&sP[wv][ridx + 4];
            pa[qf][sl] = u.s8;
        }

        // ---- O += P V ; acc_l += P . ones (row-sum in O's layout)
        __builtin_amdgcn_s_setprio(1);
#pragma unroll
        for (int qf = 0; qf < 4; ++qf) {
            acc_l[qf] = MFMA_BF16(pa[qf][0], ones, acc_l[qf]);
            acc_l[qf] = MFMA_BF16(pa[qf][1], ones, acc_l[qf]);
        }
#pragma unroll
        for (int dt = 0; dt < 4; ++dt) {
            const int row = 16 * dt + l16;
            const int swr = row & 7;
#pragma unroll
            for (int sl = 0; sl < 2; ++sl) {
                const int idx = row * 64 + (((sl << 2) | l4) ^ swr) * 8;
                short8 vh8 = *(const short8*)&sVh[cur][idx];
#pragma unroll
                for (int qf = 0; qf < 4; ++qf)
                    O[qf][dt] = MFMA_BF16(pa[qf][sl], vh8, O[qf][dt]);
            }
        }
        __builtin_amdgcn_s_setprio(0);

        __syncthreads(); // drains next-tile DMA (vmcnt 0) + barrier
        cur ^= 1;
    }

    // ---- epilogue: h = O / l -> bf16 Hb rows (l is lane-local)
#pragma unroll
    for (int qf = 0; qf < 4; ++qf) {
        f32x4 iv;
#pragma unroll
        for (int r = 0; r < 4; ++r) iv[r] = 1.0f / acc_l[qf][r];
#pragma unroll
        for (int r = 0; r < 4; ++r) {
            const int q = qr0 + qf * 16 + 4 * l4 + r;
            ushort_t* op = Hb + (size_t)(b * LL + q) * CC + h * DD + l16;
#pragma unroll
            for (int dt = 0; dt < 4; ++dt)
                op[16 * dt] = f2bf(O[qf][dt][r] * iv[r]);
        }
    }
}

// ---------------------------------------------------------------------------
// Legacy fp32 fallback kernels (only if ws_size is too small; never expected)
// ---------------------------------------------------------------------------
#define Bb 128
#define Bn 128
#define BKG 8

__global__ __launch_bounds__(256)
void gemm_bias(const float* __restrict__ A, const float* __restrict__ B,
               const float* __restrict__ bias, float* __restrict__ C,
               int M, int N, int K, int lda, int ldb, int ldc)
{
    __shared__ float As[BKG][Bb];
    __shared__ float Bs[BKG][Bn];

    const int tid = threadIdx.x;
    const int m0 = blockIdx.y * Bb;
    const int n0 = blockIdx.x * Bn;
    const int ty = tid >> 4, tx = tid & 15;
    const int arow = tid >> 1, acol = (tid & 1) * 4;
    const int brow = tid >> 5, bcol = (tid & 31) * 4;

    const float* Ap = A + (size_t)(m0 + arow) * lda + acol;
    const float* Bp = B + (size_t)brow * ldb + n0 + bcol;

    float acc[8][8];
#pragma unroll
    for (int i = 0; i < 8; ++i)
#pragma unroll
        for (int j = 0; j < 8; ++j) acc[i][j] = 0.f;

    for (int k0 = 0; k0 < K; k0 += BKG) {
        float4 av = *(const float4*)(Ap + k0);
        float4 bv = *(const float4*)(Bp + (size_t)k0 * ldb);
        __syncthreads();
        As[acol + 0][arow] = av.x;
        As[acol + 1][arow] = av.y;
        As[acol + 2][arow] = av.z;
        As[acol + 3][arow] = av.w;
        *(float4*)&Bs[brow][bcol] = bv;
        __syncthreads();
#pragma unroll
        for (int kk = 0; kk < BKG; ++kk) {
            float a[8], bvv[8];
            *(float4*)&a[0] = *(const float4*)&As[kk][ty * 4];
            *(float4*)&a[4] = *(const float4*)&As[kk][64 + ty * 4];
            *(float4*)&bvv[0] = *(const float4*)&Bs[kk][tx * 4];
            *(float4*)&bvv[4] = *(const float4*)&Bs[kk][64 + tx * 4];
#pragma unroll
            for (int i = 0; i < 8; ++i)
#pragma unroll
                for (int j = 0; j < 8; ++j)
                    acc[i][j] = fmaf(a[i], bvv[j], acc[i][j]);
        }
    }
#pragma unroll
    for (int ih = 0; ih < 2; ++ih)
#pragma unroll
    for (int i = 0; i < 4; ++i) {
        const int m = m0 + ih * 64 + ty * 4 + i;
#pragma unroll
        for (int jh = 0; jh < 2; ++jh) {
            const int n = n0 + jh * 64 + tx * 4;
            float4 o;
            o.x = acc[ih*4+i][jh*4+0] + bias[n+0];
            o.y = acc[ih*4+i][jh*4+1] + bias[n+1];
            o.z = acc[ih*4+i][jh*4+2] + bias[n+2];
            o.w = acc[ih*4+i][jh*4+3] + bias[n+3];
            *(float4*)(C + (size_t)m * ldc + n) = o;
        }
    }
}

__global__ __launch_bounds__(256)
void rmsnorm_qk(float* __restrict__ qkv,
                const float* __restrict__ gq, const float* __restrict__ gk)
{
    const int gt    = blockIdx.x * 256 + threadIdx.x;
    const int lane  = gt & 63;
    const int wave  = gt >> 6;
    const int which = wave & 1;
    const int h     = (wave >> 1) & (HH - 1);
    const int bl    = wave >> 5;

    float* p = qkv + (size_t)bl * (3 * CC) + which * CC + h * DD + lane;
    float v = *p;
    float ss = v * v;
#pragma unroll
    for (int off = 32; off; off >>= 1) ss += __shfl_xor(ss, off);
    float nrm = fmaxf(sqrtf(ss), 1e-12f);
    const float* g = which ? gk : gq;
    *p = v * (8.0f / nrm) * g[h * DD + lane];
}

__global__ __launch_bounds__(256)
void flash_fp32(float* __restrict__ qkv)
{
    const int qt = blockIdx.x, hh = blockIdx.y, bb = blockIdx.z;

    __shared__ float Qt[DD][64];
    __shared__ float Kt[DD][64];
    __shared__ float Vs[64][DD];
    __shared__ float Ps[64][64 + 4];

    const int tid = threadIdx.x;
    const int ty = tid >> 4, tx = tid & 15;
    const size_t rs_ = 3 * CC;
    const float* qbase = qkv + ((size_t)bb * LL + (size_t)qt * 64) * rs_ + hh * DD;
    const float* kbase = qkv + (size_t)bb * LL * rs_ + CC + hh * DD;
    const float* vbase = kbase + CC;

    {
        const int r = tid >> 2, c0 = (tid & 3) * 16;
#pragma unroll
        for (int u = 0; u < 4; ++u) {
            float4 v = *(const float4*)(qbase + (size_t)r * rs_ + c0 + u * 4);
            Qt[c0 + u*4 + 0][r] = v.x; Qt[c0 + u*4 + 1][r] = v.y;
            Qt[c0 + u*4 + 2][r] = v.z; Qt[c0 + u*4 + 3][r] = v.w;
        }
    }

    float mrow[4], lrow[4], O[4][4];
#pragma unroll
    for (int i = 0; i < 4; ++i) {
        mrow[i] = -INFINITY; lrow[i] = 0.f;
#pragma unroll
        for (int j = 0; j < 4; ++j) O[i][j] = 0.f;
    }

    for (int kt = 0; kt < LL / 64; ++kt) {
        __syncthreads();
        {
            const int r = tid >> 2, c0 = (tid & 3) * 16;
            const float* kr = kbase + ((size_t)kt * 64 + r) * rs_;
            const float* vr = vbase + ((size_t)kt * 64 + r) * rs_;
#pragma unroll
            for (int u = 0; u < 4; ++u) {
                float4 kv = *(const float4*)(kr + c0 + u * 4);
                Kt[c0 + u*4 + 0][r] = kv.x; Kt[c0 + u*4 + 1][r] = kv.y;
                Kt[c0 + u*4 + 2][r] = kv.z; Kt[c0 + u*4 + 3][r] = kv.w;
                *(float4*)&Vs[r][c0 + u*4] = *(const float4*)(vr + c0 + u * 4);
            }
        }
        __syncthreads();

        float S[4][4];
#pragma unroll
        for (int i = 0; i < 4; ++i)
#pragma unroll
            for (int j = 0; j < 4; ++j) S[i][j] = 0.f;
#pragma unroll 8
        for (int d = 0; d < DD; ++d) {
            float a[4], b[4];
            *(float4*)a = *(const float4*)&Qt[d][ty * 4];
            *(float4*)b = *(const float4*)&Kt[d][tx * 4];
#pragma unroll
            for (int i = 0; i < 4; ++i)
#pragma unroll
                for (int j = 0; j < 4; ++j) S[i][j] = fmaf(a[i], b[j], S[i][j]);
        }
#pragma unroll
        for (int i = 0; i < 4; ++i) {
#pragma unroll
            for (int j = 0; j < 4; ++j) S[i][j] *= 0.125f;
            float pm = fmaxf(fmaxf(S[i][0], S[i][1]), fmaxf(S[i][2], S[i][3]));
#pragma unroll
            for (int off = 1; off < 16; off <<= 1) pm = fmaxf(pm, __shfl_xor(pm, off));
            const float mnew = fmaxf(mrow[i], pm);
            const float corr = __expf(mrow[i] - mnew);
            float rsum = 0.f;
#pragma unroll
            for (int j = 0; j < 4; ++j) { S[i][j] = __expf(S[i][j] - mnew); rsum += S[i][j]; }
#pragma unroll
            for (int off = 1; off < 16; off <<= 1) rsum += __shfl_xor(rsum, off);
            mrow[i] = mnew;
            lrow[i] = lrow[i] * corr + rsum;
#pragma unroll
            for (int j = 0; j < 4; ++j) O[i][j] *= corr;
        }
#pragma unroll
        for (int i = 0; i < 4; ++i)
            *(float4*)&Ps[ty * 4 + i][tx * 4] = *(float4*)&S[i][0];
        __syncthreads();
#pragma unroll 4
        for (int k = 0; k < 64; k += 4) {
            float a[4][4];
#pragma unroll
            for (int i = 0; i < 4; ++i)
                *(float4*)&a[i][0] = *(const float4*)&Ps[ty * 4 + i][k];
#pragma unroll
            for (int kk = 0; kk < 4; ++kk) {
                float bv[4];
                *(float4*)bv = *(const float4*)&Vs[k + kk][tx * 4];
#pragma unroll
                for (int i = 0; i < 4; ++i)
#pragma unroll
                    for (int j = 0; j < 4; ++j)
                        O[i][j] = fmaf(a[i][kk], bv[j], O[i][j]);
            }
        }
    }

    float* obase = qkv + ((size_t)bb * LL + (size_t)qt * 64) * rs_ + hh * DD;
#pragma unroll
    for (int i = 0; i < 4; ++i) {
        const float inv = 1.f / lrow[i];
        float4 o;
        o.x = O[i][0] * inv; o.y = O[i][1] * inv;
        o.z = O[i][2] * inv; o.w = O[i][3] * inv;
        *(float4*)(obase + (size_t)(ty * 4 + i) * rs_ + tx * 4) = o;
    }
}

// ---------------------------------------------------------------------------
extern "C" void kernel_launch(void* const* d_in, const int* in_sizes, int n_in,
                              void* d_out, int out_size, void* d_ws, size_t ws_size,
                              hipStream_t stream)
{
    const float* x    = (const float*)d_in[0];
    const float* Wqkv = (const float*)d_in[1];
    const float* bqkv = (const float*)d_in[2];
    const float* gq   = (const float*)d_in[3];
    const float* gk   = (const float*)d_in[4];
    const float* Wout = (const float*)d_in[5];
    const float* bout = (const float*)d_in[6];
    float* out = (float*)d_out;

    const size_t NEED = 92274688ull; // 88 MiB (proven available)

    if (ws_size >= NEED) {
        char* wsb = (char*)d_ws;
        ushort_t* Qbh = (ushort_t*)(wsb);                 // 16 MiB
        ushort_t* Kh  = (ushort_t*)(wsb + 16777216);      // 16 MiB
        ushort_t* Vth = (ushort_t*)(wsb + 33554432);      // 16 MiB
        ushort_t* Hb  = (ushort_t*)(wsb + 50331648);      // 16 MiB
        ushort_t* wqh = (ushort_t*)(wsb + 67108864);      // 6 MiB
        ushort_t* woh = (ushort_t*)(wsb + 73400320);      // 2 MiB
        ushort_t* xh  = (ushort_t*)(wsb + 75497472);      // 16 MiB

        // one fused prep launch: x->bf16 (4096 blocks) + WqkvT (768) + WoutT (256)
        prep_all<<<dim3(4096 + 768 + 256), 256, 0, stream>>>(
            x, xh, Wqkv, wqh, Wout, woh);

        gemm_qkv<<<dim3(24 * 64), 256, 0, stream>>>(
            xh, wqh, bqkv, gq, gk, Qbh, Kh, Vth);

        flash12<<<dim3(512), 256, 0, stream>>>(Qbh, Kh, Vth, Hb);

        gemm_out1<<<dim3(8 * 64), 256, 0, stream>>>(Hb, woh, bout, out);
    } else {
        // legacy fp32 path
        float* qkv = (float*)d_ws;
        gemm_bias<<<dim3((3 * CC) / Bn, MM / Bb), 256, 0, stream>>>(
            x, Wqkv, bqkv, qkv, MM, 3 * CC, CC, CC, 3 * CC, 3 * CC);
        rmsnorm_qk<<<dim3((MM * HH * 2 * 64) / 256), 256, 0, stream>>>(qkv, gq, gk);
        flash_fp32<<<dim3(LL / 64, HH, BB), 256, 0, stream>>>(qkv);
        gemm_bias<<<dim3(CC / Bn, MM / Bb), 256, 0, stream>>>(
            qkv, Wout, bout, out, MM, CC, CC, 3 * CC, CC, CC);
    }
}

// Round 20
// 188.199 us; speedup vs baseline: 1.0075x; 1.0075x over previous
//
#include <hip/hip_runtime.h>
#include <math.h>

// Problem constants (B=4, L=2048, C=1024, H=16, D=64)
#define BB 4
#define LL 2048
#define CC 1024
#define HH 16
#define DD 64
#define MM (BB * LL) // 8192 rows

typedef float f32x4 __attribute__((ext_vector_type(4)));
typedef short short8 __attribute__((ext_vector_type(8))); // 8 bf16 (4 VGPRs)
typedef unsigned short ushort_t;
typedef unsigned long long u64_t;

#define MFMA_BF16(A, B, C) __builtin_amdgcn_mfma_f32_16x16x32_bf16(A, B, C, 0, 0, 0)

// q pre-scale: 1/sqrt(D) * log2(e), so softmax runs in exp2 domain
#define QSCALE 0.180336880f

__device__ __forceinline__ unsigned short f2bf(float x) {
    unsigned int u = __float_as_uint(x);
    u += 0x7fffu + ((u >> 16) & 1u); // RTN-even
    return (unsigned short)(u >> 16);
}

// pack two positive f32 into (bf16(b)<<16)|bf16(a), round-half-up via +0x8000
__device__ __forceinline__ unsigned pack_bf2(float a, float b) {
#if __has_builtin(__builtin_amdgcn_perm)
    return __builtin_amdgcn_perm(__float_as_uint(b) + 0x8000u,
                                 __float_as_uint(a) + 0x8000u, 0x07060302u);
#else
    return ((__float_as_uint(b) + 0x8000u) & 0xFFFF0000u) |
           ((__float_as_uint(a) + 0x8000u) >> 16);
#endif
}

// raw v_exp_f32 (domain here has no denormals; skip libm fixup)
__device__ __forceinline__ float fast_exp2(float x) {
#if __has_builtin(__builtin_amdgcn_exp2f)
    return __builtin_amdgcn_exp2f(x);
#else
    return exp2f(x);
#endif
}

// ---------------------------------------------------------------------------
// Fused prep: one launch.
//   blocks [0, 4096):        x f32 -> bf16 xh
//   blocks [4096, 4864):     Wqkv transpose+round -> wqh [3C][C]
//   blocks [4864, 5120):     Wout transpose+round -> woh [C][C]
// ---------------------------------------------------------------------------
__global__ __launch_bounds__(256)
void prep_all(const float* __restrict__ x, ushort_t* __restrict__ xh,
              const float* __restrict__ Wq, ushort_t* __restrict__ Tq,
              const float* __restrict__ Wo, ushort_t* __restrict__ To)
{
    __shared__ float sT[64][65];
    int bid = blockIdx.x;
    const int tid = threadIdx.x;

    if (bid < 4096) { // x rounding: 8 f32 per thread
        const int i = (bid * 256 + tid) * 8;
        f32x4 a = *(const f32x4*)(x + i);
        f32x4 b = *(const f32x4*)(x + i + 4);
        short8 h;
#pragma unroll
        for (int j = 0; j < 4; ++j) {
            h[j]     = (short)f2bf(a[j]);
            h[4 + j] = (short)f2bf(b[j]);
        }
        *(short8*)(xh + i) = h;
        return;
    }
    bid -= 4096;

    const float* W;
    ushort_t* T;
    int N, bx, by;
    if (bid < 768) { W = Wq; T = Tq; N = 3 * CC; bx = bid % 48; by = bid / 48; }
    else { bid -= 768; W = Wo; T = To; N = CC; bx = bid % 16; by = bid / 16; }

    const int K = CC;
    const int k0 = by * 64, n0 = bx * 64;
    const int r = tid >> 2, c0 = (tid & 3) * 16;

    const float* wp = W + (size_t)(k0 + r) * N + n0 + c0;
#pragma unroll
    for (int u = 0; u < 4; ++u) {
        f32x4 v = *(const f32x4*)(wp + 4 * u);
        sT[r][c0 + 4 * u + 0] = v[0];
        sT[r][c0 + 4 * u + 1] = v[1];
        sT[r][c0 + 4 * u + 2] = v[2];
        sT[r][c0 + 4 * u + 3] = v[3];
    }
    __syncthreads();

    const int nn = tid >> 2, kk0 = (tid & 3) * 16;
    short8 h0, h1;
#pragma unroll
    for (int u = 0; u < 8; ++u) {
        h0[u] = (short)f2bf(sT[kk0 + u][nn]);
        h1[u] = (short)f2bf(sT[kk0 + 8 + u][nn]);
    }
    ushort_t* oh = T + (size_t)(n0 + nn) * K + k0 + kk0;
    *(short8*)oh = h0; *(short8*)(oh + 8) = h1;
}

// ---------------------------------------------------------------------------
// Fused QKV GEMM, single-term bf16, next-K-tile register prefetch.
// Epilogue: rmsnorm q -> bf16 Qbh (xQSCALE), rmsnorm k -> bf16 Kh
// [b][h][l][d], v -> bf16 Vth transposed [b][h][d][l].
// ---------------------------------------------------------------------------
__global__ __launch_bounds__(256, 3)
void gemm_qkv(const ushort_t* __restrict__ Agh,
              const ushort_t* __restrict__ Bh,
              const float* __restrict__ bias,
              const float* __restrict__ gq, const float* __restrict__ gk,
              ushort_t* __restrict__ Qbh,
              ushort_t* __restrict__ Kh,
              ushort_t* __restrict__ Vth)
{
    __shared__ ushort_t smem[16384]; // 32 KB
    ushort_t* sAh = smem;
    ushort_t* sBh = smem + 8192;

    const int K = CC, lda = CC, nbx = (3 * CC) / 128; // 24

    const int nwg = gridDim.x;
    const int cpx = nwg >> 3;
    const int id  = blockIdx.x;
    const int swz = (id & 7) * cpx + (id >> 3);
    const int bx = swz % nbx, by = swz / nbx;
    const int m0 = by * 128, n0 = bx * 128;

    const int tid  = threadIdx.x;
    const int lane = tid & 63;
    const int wv   = tid >> 6;
    const int l4   = lane >> 4, l16 = lane & 15;
    const int wm   = wv >> 1,  wn  = wv & 1;

    const int r0  = tid >> 2;
    const int c0  = (tid & 3) * 16;
    const int ch0 = c0 >> 3;

    f32x4 acc[4][4];
#pragma unroll
    for (int i = 0; i < 4; ++i)
#pragma unroll
        for (int j = 0; j < 4; ++j) acc[i][j] = 0.f;

    short8 stgA[4], stgB[4];
#pragma unroll
    for (int it = 0; it < 2; ++it) {
        const ushort_t* ahp = Agh + (size_t)(m0 + r0 + 64 * it) * lda + c0;
        stgA[2 * it]     = *(const short8*)(ahp);
        stgA[2 * it + 1] = *(const short8*)(ahp + 8);
        const ushort_t* bhp = Bh + (size_t)(n0 + r0 + 64 * it) * K + c0;
        stgB[2 * it]     = *(const short8*)(bhp);
        stgB[2 * it + 1] = *(const short8*)(bhp + 8);
    }

    for (int kt = 0; kt < K; kt += 64) {
        __syncthreads();
#pragma unroll
        for (int it = 0; it < 2; ++it) {
            const int row  = r0 + 64 * it;
            const int sA   = row & 7;
            const int base = row * 64;
            const int cA = ((ch0) ^ sA) * 8, cB = ((ch0 + 1) ^ sA) * 8;
            *(short8*)&sAh[base + cA] = stgA[2 * it];
            *(short8*)&sAh[base + cB] = stgA[2 * it + 1];
            *(short8*)&sBh[base + cA] = stgB[2 * it];
            *(short8*)&sBh[base + cB] = stgB[2 * it + 1];
        }
        __syncthreads();

        if (kt + 64 < K) { // prefetch next K-tile (overlaps MFMA below)
#pragma unroll
            for (int it = 0; it < 2; ++it) {
                const ushort_t* ahp = Agh + (size_t)(m0 + r0 + 64 * it) * lda + kt + 64 + c0;
                stgA[2 * it]     = *(const short8*)(ahp);
                stgA[2 * it + 1] = *(const short8*)(ahp + 8);
                const ushort_t* bhp = Bh + (size_t)(n0 + r0 + 64 * it) * K + kt + 64 + c0;
                stgB[2 * it]     = *(const short8*)(bhp);
                stgB[2 * it + 1] = *(const short8*)(bhp + 8);
            }
        }

#pragma unroll
        for (int ks = 0; ks < 2; ++ks) {
            const int chf = (((ks << 2) | l4) ^ (l16 & 7)) * 8;
            short8 fbh[4];
#pragma unroll
            for (int j = 0; j < 4; ++j) {
                const int idx = (64 * wn + 16 * j + l16) * 64 + chf;
                fbh[j] = *(const short8*)&sBh[idx];
            }
#pragma unroll
            for (int i = 0; i < 4; ++i) {
                const int idx = (64 * wm + 16 * i + l16) * 64 + chf;
                short8 fah = *(const short8*)&sAh[idx];
#pragma unroll
                for (int j = 0; j < 4; ++j)
                    acc[i][j] = MFMA_BF16(fah, fbh[j], acc[i][j]);
            }
        }
    }

    // ---- epilogue -------------------------------------------------------
    const int region = n0 >> 10; // 0=q, 1=k, 2=v
    float bv[4];
#pragma unroll
    for (int j = 0; j < 4; ++j) bv[j] = bias[n0 + 64 * wn + 16 * j + l16];
#pragma unroll
    for (int i = 0; i < 4; ++i)
#pragma unroll
        for (int j = 0; j < 4; ++j)
#pragma unroll
            for (int r = 0; r < 4; ++r) acc[i][j][r] += bv[j];

    const int b = m0 >> 11;

    if (region < 2) {
        const int hloc = ((n0 & 1023) >> 6) + wn;
        const float* g = (region == 0 ? gq : gk) + hloc * DD;
        float gv[4];
#pragma unroll
        for (int j = 0; j < 4; ++j) gv[j] = g[16 * j + l16];
#pragma unroll
        for (int i = 0; i < 4; ++i)
#pragma unroll
        for (int r = 0; r < 4; ++r) {
            float ss = 0.f;
#pragma unroll
            for (int j = 0; j < 4; ++j) ss += acc[i][j][r] * acc[i][j][r];
#pragma unroll
            for (int off = 1; off < 16; off <<= 1) ss += __shfl_xor(ss, off);
            const float s = 8.0f / fmaxf(sqrtf(ss), 1e-12f);
#pragma unroll
            for (int j = 0; j < 4; ++j) acc[i][j][r] *= s * gv[j];
        }

        if (region == 0) {
            // q: bf16, pre-scaled for exp2-domain softmax
#pragma unroll
            for (int i = 0; i < 4; ++i)
#pragma unroll
            for (int r = 0; r < 4; ++r) {
                const int row = m0 + 64 * wm + 16 * i + 4 * l4 + r;
                ushort_t* op = Qbh + (size_t)row * CC + n0 + 64 * wn + l16;
#pragma unroll
                for (int j = 0; j < 4; ++j)
                    op[16 * j] = f2bf(acc[i][j][r] * QSCALE);
            }
        } else {
            const int hk = ((n0 - 1024) >> 6) + wn;
#pragma unroll
            for (int i = 0; i < 4; ++i)
#pragma unroll
            for (int r = 0; r < 4; ++r) {
                const int l = (m0 & 2047) + 64 * wm + 16 * i + 4 * l4 + r;
                const size_t base = ((size_t)(b * HH + hk) * LL + l) * DD + l16;
#pragma unroll
                for (int j = 0; j < 4; ++j)
                    Kh[base + 16 * j] = f2bf(acc[i][j][r]);
            }
        }
    } else {
        // V: bf16 + 128x128 LDS transpose + vector store to [b][h][d][l]
        __syncthreads();
        ushort_t* vh = smem; // [128][128] = 32 KB exactly
#pragma unroll
        for (int i = 0; i < 4; ++i)
#pragma unroll
        for (int r = 0; r < 4; ++r) {
            const int lr = 64 * wm + 16 * i + 4 * l4 + r;
#pragma unroll
            for (int j = 0; j < 4; ++j) {
                const int c = 64 * wn + 16 * j + l16;
                vh[lr * 128 + c] = f2bf(acc[i][j][r]);
            }
        }
        __syncthreads();
        const int c    = tid & 127;
        const int half = tid >> 7;
        const int hv   = ((n0 - 2048) >> 6) + (c >> 6);
        const int d    = c & 63;
        ushort_t* oh = Vth + ((size_t)(b * HH + hv) * DD + d) * LL + (m0 & 2047) + half * 64;
#pragma unroll
        for (int u = 0; u < 8; ++u) {
            const int l0 = half * 64 + u * 8;
            short8 hv8;
#pragma unroll
            for (int e = 0; e < 8; ++e)
                hv8[e] = (short)vh[(l0 + e) * 128 + c];
            *(short8*)&oh[u * 8] = hv8;
        }
    }
}

// ---------------------------------------------------------------------------
// Output projection, single-term bf16 with register prefetch.
// ---------------------------------------------------------------------------
__global__ __launch_bounds__(256, 3)
void gemm_out1(const ushort_t* __restrict__ Ah,
               const ushort_t* __restrict__ Bh,
               const float* __restrict__ bias, float* __restrict__ Cg)
{
    __shared__ ushort_t sAh[8192];
    __shared__ ushort_t sBh[8192];

    const int K = CC, nbx = CC / 128; // 8

    const int nwg = gridDim.x;
    const int cpx = nwg >> 3;
    const int id  = blockIdx.x;
    const int sw  = (id & 7) * cpx + (id >> 3);
    const int bx = sw % nbx, by = sw / nbx;
    const int m0 = by * 128, n0 = bx * 128;

    const int tid  = threadIdx.x;
    const int lane = tid & 63;
    const int wv   = tid >> 6;
    const int l4   = lane >> 4, l16 = lane & 15;
    const int wm   = wv >> 1,  wn  = wv & 1;

    const int r0  = tid >> 2;
    const int c0  = (tid & 3) * 16;
    const int ch0 = c0 >> 3;

    f32x4 acc[4][4];
#pragma unroll
    for (int i = 0; i < 4; ++i)
#pragma unroll
        for (int j = 0; j < 4; ++j) acc[i][j] = 0.f;

    short8 stgA[4], stgB[4];
#pragma unroll
    for (int it = 0; it < 2; ++it) {
        const ushort_t* ahp = Ah + (size_t)(m0 + r0 + 64 * it) * CC + c0;
        stgA[2 * it]     = *(const short8*)(ahp);
        stgA[2 * it + 1] = *(const short8*)(ahp + 8);
        const ushort_t* bhp = Bh + (size_t)(n0 + r0 + 64 * it) * K + c0;
        stgB[2 * it]     = *(const short8*)(bhp);
        stgB[2 * it + 1] = *(const short8*)(bhp + 8);
    }

    for (int kt = 0; kt < K; kt += 64) {
        __syncthreads();
#pragma unroll
        for (int it = 0; it < 2; ++it) {
            const int row  = r0 + 64 * it;
            const int sA   = row & 7;
            const int base = row * 64;
            const int cA = ((ch0) ^ sA) * 8, cB = ((ch0 + 1) ^ sA) * 8;
            *(short8*)&sAh[base + cA] = stgA[2 * it];
            *(short8*)&sAh[base + cB] = stgA[2 * it + 1];
            *(short8*)&sBh[base + cA] = stgB[2 * it];
            *(short8*)&sBh[base + cB] = stgB[2 * it + 1];
        }
        __syncthreads();

        if (kt + 64 < K) { // prefetch next K-tile
#pragma unroll
            for (int it = 0; it < 2; ++it) {
                const ushort_t* ahp = Ah + (size_t)(m0 + r0 + 64 * it) * CC + kt + 64 + c0;
                stgA[2 * it]     = *(const short8*)(ahp);
                stgA[2 * it + 1] = *(const short8*)(ahp + 8);
                const ushort_t* bhp = Bh + (size_t)(n0 + r0 + 64 * it) * K + kt + 64 + c0;
                stgB[2 * it]     = *(const short8*)(bhp);
                stgB[2 * it + 1] = *(const short8*)(bhp + 8);
            }
        }

#pragma unroll
        for (int ks = 0; ks < 2; ++ks) {
            const int chf = (((ks << 2) | l4) ^ (l16 & 7)) * 8;
            short8 fbh[4];
#pragma unroll
            for (int j = 0; j < 4; ++j) {
                const int idx = (64 * wn + 16 * j + l16) * 64 + chf;
                fbh[j] = *(const short8*)&sBh[idx];
            }
#pragma unroll
            for (int i = 0; i < 4; ++i) {
                const int idx = (64 * wm + 16 * i + l16) * 64 + chf;
                short8 fah = *(const short8*)&sAh[idx];
#pragma unroll
                for (int j = 0; j < 4; ++j)
                    acc[i][j] = MFMA_BF16(fah, fbh[j], acc[i][j]);
            }
        }
    }

    float bv[4];
#pragma unroll
    for (int j = 0; j < 4; ++j) bv[j] = bias[n0 + 64 * wn + 16 * j + l16];
#pragma unroll
    for (int i = 0; i < 4; ++i)
#pragma unroll
    for (int r = 0; r < 4; ++r) {
        const int row = m0 + 64 * wm + 16 * i + 4 * l4 + r;
        float* cp = Cg + (size_t)row * CC + n0 + 64 * wn + l16;
#pragma unroll
        for (int j = 0; j < 4; ++j) cp[16 * j] = acc[i][j][r] + bv[j];
    }
}

// ---------------------------------------------------------------------------
// Flash attention v13 = v11 (proven 87.4 us) + ping-pong staging registers:
// global loads for tile t+1 are issued BEFORE the ds_write of tile t
// (hiding window = ds_write + barrier + compute). Explicit even/odd unroll
// keeps all stg indexing compile-time constant (no scratch).
// QF=4 (64 q-rows/wave), fixed-shift exp2 softmax, KVBLK=64, zero conflicts,
// row-sum l via MFMA(P, ones).
// ---------------------------------------------------------------------------
__global__ __launch_bounds__(256, 2)
void flash13(const ushort_t* __restrict__ Qbh,
             const ushort_t* __restrict__ Kh,
             const ushort_t* __restrict__ Vth,
             ushort_t* __restrict__ Hb)
{
    __shared__ ushort_t sKh[4096], sVh[4096]; // 16 KB
    __shared__ ushort_t sP[4][64 * 68];       // 34 KB

    const int i    = blockIdx.x;          // 0..511
    const int xcd  = i & 7;
    const int slot = i >> 3;              // 0..63
    const int qt   = slot & 7;            // 8 q-tiles of 256 rows
    const int bh   = ((slot >> 3) << 3) | xcd;
    const int b    = bh >> 4, h = bh & 15;

    const int tid  = threadIdx.x;
    const int lane = tid & 63;
    const int wv   = tid >> 6;
    const int l4   = lane >> 4, l16 = lane & 15;

    // ---- Q fragments: 4 q-frags per wave (64 rows), pre-scaled bf16
    short8 qh[4][2];
    const int qr0 = qt * 256 + wv * 64;
#pragma unroll
    for (int qf = 0; qf < 4; ++qf)
#pragma unroll
    for (int sl = 0; sl < 2; ++sl)
        qh[qf][sl] = *(const short8*)(Qbh + (size_t)(b * LL + qr0 + qf * 16 + l16) * CC
                                      + h * DD + sl * 32 + l4 * 8);

    // bf16 1.0 vector for the MFMA row-sum
    short8 ones;
#pragma unroll
    for (int j = 0; j < 8; ++j) ones[j] = (short)0x3F80;

    f32x4 O[4][4];
    f32x4 acc_l[4];   // row-sum of P, layout q = 4*l4 + r (same as O rows)
#pragma unroll
    for (int qf = 0; qf < 4; ++qf) {
        acc_l[qf] = 0.f;
#pragma unroll
        for (int t = 0; t < 4; ++t) O[qf][t] = 0.f;
    }

    const int r_ = tid >> 2;          // staging row 0..63
    const int c2 = (tid & 3) * 2;     // chunk pair
    const size_t kgb0 = ((size_t)bh * LL + r_) * DD + c2 * 8;
    const size_t vgb0 = ((size_t)bh * DD + r_) * LL + c2 * 8;

    short8 stgA[4], stgB[4];
    // tile 0 -> stgA
    stgA[0] = *(const short8*)&Kh[kgb0];      stgA[1] = *(const short8*)&Kh[kgb0 + 8];
    stgA[2] = *(const short8*)&Vth[vgb0];     stgA[3] = *(const short8*)&Vth[vgb0 + 8];

    // one KV-tile step: cur holds tile kt (to be written to LDS), nxt gets
    // the loads for tile kt+1 issued BEFORE the ds_write of cur.
#define FLASH_STEP(cur, nxt, kt)                                               \
    {                                                                          \
        __syncthreads(); /* previous tile fully consumed */                    \
        if ((kt) + 1 < LL / 64) { /* issue next-tile loads early */            \
            const size_t kgb = kgb0 + (size_t)((kt) + 1) * 64 * DD;            \
            const size_t vgb = vgb0 + (size_t)((kt) + 1) * 64;                 \
            nxt[0] = *(const short8*)&Kh[kgb];                                 \
            nxt[1] = *(const short8*)&Kh[kgb + 8];                             \
            nxt[2] = *(const short8*)&Vth[vgb];                                \
            nxt[3] = *(const short8*)&Vth[vgb + 8];                            \
        }                                                                      \
        {                                                                      \
            const int wr = r_ * 64, s = r_ & 7;                                \
            const int cA = ((c2) ^ s) * 8, cB = ((c2 + 1) ^ s) * 8;            \
            *(short8*)&sKh[wr + cA] = cur[0];                                  \
            *(short8*)&sKh[wr + cB] = cur[1];                                  \
            *(short8*)&sVh[wr + cA] = cur[2];                                  \
            *(short8*)&sVh[wr + cB] = cur[3];                                  \
        }                                                                      \
        __syncthreads();                                                       \
        f32x4 S[4][4];                                                         \
        _Pragma("unroll")                                                      \
        for (int qf = 0; qf < 4; ++qf)                                         \
            _Pragma("unroll")                                                  \
            for (int t = 0; t < 4; ++t) S[qf][t] = 0.f;                        \
        __builtin_amdgcn_s_setprio(1);                                         \
        _Pragma("unroll")                                                      \
        for (int t = 0; t < 4; ++t) {                                          \
            const int row = 16 * t + l16;                                      \
            const int swr = row & 7;                                           \
            _Pragma("unroll")                                                  \
            for (int sl = 0; sl < 2; ++sl) {                                   \
                const int idx = row * 64 + (((sl << 2) | l4) ^ swr) * 8;       \
                short8 kh8 = *(const short8*)&sKh[idx];                        \
                _Pragma("unroll")                                              \
                for (int qf = 0; qf < 4; ++qf)                                 \
                    S[qf][t] = MFMA_BF16(kh8, qh[qf][sl], S[qf][t]);           \
            }                                                                  \
        }                                                                      \
        __builtin_amdgcn_s_setprio(0);                                         \
        _Pragma("unroll")                                                      \
        for (int qf = 0; qf < 4; ++qf)                                         \
            _Pragma("unroll")                                                  \
            for (int t = 0; t < 4; ++t)                                        \
                _Pragma("unroll")                                              \
                for (int r = 0; r < 4; ++r)                                    \
                    S[qf][t][r] = fast_exp2(S[qf][t][r]);                      \
        _Pragma("unroll")                                                      \
        for (int qf = 0; qf < 4; ++qf)                                         \
            _Pragma("unroll")                                                  \
            for (int t = 0; t < 4; ++t) {                                      \
                unsigned lo = pack_bf2(S[qf][t][0], S[qf][t][1]);              \
                unsigned hi = pack_bf2(S[qf][t][2], S[qf][t][3]);              \
                const int widx = (qf * 16 + l16) * 68 + 16 * t + 4 * l4;       \
                *(u64_t*)&sP[wv][widx] = (u64_t)lo | ((u64_t)hi << 32);        \
            }                                                                  \
        asm volatile("s_waitcnt lgkmcnt(0)" ::: "memory");                     \
        __builtin_amdgcn_sched_barrier(0);                                     \
        short8 pa[4][2];                                                       \
        _Pragma("unroll")                                                      \
        for (int qf = 0; qf < 4; ++qf)                                         \
            _Pragma("unroll")                                                  \
            for (int sl = 0; sl < 2; ++sl) {                                   \
                const int ridx = (qf * 16 + l16) * 68 + sl * 32 + 8 * l4;      \
                union { u64_t q[2]; short8 s8; } u;                            \
                u.q[0] = *(const u64_t*)&sP[wv][ridx];                         \
                u.q[1] = *(const u64_t*)&sP[wv][ridx + 4];                     \
                pa[qf][sl] = u.s8;                                             \
            }                                                                  \
        __builtin_amdgcn_s_setprio(1);                                         \
        _Pragma("unroll")                                                      \
        for (int qf = 0; qf < 4; ++qf) {                                       \
            acc_l[qf] = MFMA_BF16(pa[qf][0], ones, acc_l[qf]);                 \
            acc_l[qf] = MFMA_BF16(pa[qf][1], ones, acc_l[qf]);                 \
        }                                                                      \
        _Pragma("unroll")                                                      \
        for (int dt = 0; dt < 4; ++dt) {                                       \
            const int row = 16 * dt + l16;                                     \
            const int swr = row & 7;                                           \
            _Pragma("unroll")                                                  \
            for (int sl = 0; sl < 2; ++sl) {                                   \
                const int idx = row * 64 + (((sl << 2) | l4) ^ swr) * 8;       \
                short8 vh8 = *(const short8*)&sVh[idx];                        \
                _Pragma("unroll")                                              \
                for (int qf = 0; qf < 4; ++qf)                                 \
                    O[qf][dt] = MFMA_BF16(pa[qf][sl], vh8, O[qf][dt]);         \
            }                                                                  \
        }                                                                      \
        __builtin_amdgcn_s_setprio(0);                                         \
    }

    for (int kt = 0; kt < LL / 64; kt += 2) {
        FLASH_STEP(stgA, stgB, kt);
        FLASH_STEP(stgB, stgA, kt + 1);
    }
#undef FLASH_STEP

    // ---- epilogue: h = O / l -> bf16 Hb rows (l is lane-local)
#pragma unroll
    for (int qf = 0; qf < 4; ++qf) {
        f32x4 iv;
#pragma unroll
        for (int r = 0; r < 4; ++r) iv[r] = 1.0f / acc_l[qf][r];
#pragma unroll
        for (int r = 0; r < 4; ++r) {
            const int q = qr0 + qf * 16 + 4 * l4 + r;
            ushort_t* op = Hb + (size_t)(b * LL + q) * CC + h * DD + l16;
#pragma unroll
            for (int dt = 0; dt < 4; ++dt)
                op[16 * dt] = f2bf(O[qf][dt][r] * iv[r]);
        }
    }
}

// ---------------------------------------------------------------------------
// Legacy fp32 fallback kernels (only if ws_size is too small; never expected)
// ---------------------------------------------------------------------------
#define Bb 128
#define Bn 128
#define BKG 8

__global__ __launch_bounds__(256)
void gemm_bias(const float* __restrict__ A, const float* __restrict__ B,
               const float* __restrict__ bias, float* __restrict__ C,
               int M, int N, int K, int lda, int ldb, int ldc)
{
    __shared__ float As[BKG][Bb];
    __shared__ float Bs[BKG][Bn];

    const int tid = threadIdx.x;
    const int m0 = blockIdx.y * Bb;
    const int n0 = blockIdx.x * Bn;
    const int ty = tid >> 4, tx = tid & 15;
    const int arow = tid >> 1, acol = (tid & 1) * 4;
    const int brow = tid >> 5, bcol = (tid & 31) * 4;

    const float* Ap = A + (size_t)(m0 + arow) * lda + acol;
    const float* Bp = B + (size_t)brow * ldb + n0 + bcol;

    float acc[8][8];
#pragma unroll
    for (int i = 0; i < 8; ++i)
#pragma unroll
        for (int j = 0; j < 8; ++j) acc[i][j] = 0.f;

    for (int k0 = 0; k0 < K; k0 += BKG) {
        float4 av = *(const float4*)(Ap + k0);
        float4 bv = *(const float4*)(Bp + (size_t)k0 * ldb);
        __syncthreads();
        As[acol + 0][arow] = av.x;
        As[acol + 1][arow] = av.y;
        As[acol + 2][arow] = av.z;
        As[acol + 3][arow] = av.w;
        *(float4*)&Bs[brow][bcol] = bv;
        __syncthreads();
#pragma unroll
        for (int kk = 0; kk < BKG; ++kk) {
            float a[8], bvv[8];
            *(float4*)&a[0] = *(const float4*)&As[kk][ty * 4];
            *(float4*)&a[4] = *(const float4*)&As[kk][64 + ty * 4];
            *(float4*)&bvv[0] = *(const float4*)&Bs[kk][tx * 4];
            *(float4*)&bvv[4] = *(const float4*)&Bs[kk][64 + tx * 4];
#pragma unroll
            for (int i = 0; i < 8; ++i)
#pragma unroll
                for (int j = 0; j < 8; ++j)
                    acc[i][j] = fmaf(a[i], bvv[j], acc[i][j]);
        }
    }
#pragma unroll
    for (int ih = 0; ih < 2; ++ih)
#pragma unroll
    for (int i = 0; i < 4; ++i) {
        const int m = m0 + ih * 64 + ty * 4 + i;
#pragma unroll
        for (int jh = 0; jh < 2; ++jh) {
            const int n = n0 + jh * 64 + tx * 4;
            float4 o;
            o.x = acc[ih*4+i][jh*4+0] + bias[n+0];
            o.y = acc[ih*4+i][jh*4+1] + bias[n+1];
            o.z = acc[ih*4+i][jh*4+2] + bias[n+2];
            o.w = acc[ih*4+i][jh*4+3] + bias[n+3];
            *(float4*)(C + (size_t)m * ldc + n) = o;
        }
    }
}

__global__ __launch_bounds__(256)
void rmsnorm_qk(float* __restrict__ qkv,
                const float* __restrict__ gq, const float* __restrict__ gk)
{
    const int gt    = blockIdx.x * 256 + threadIdx.x;
    const int lane  = gt & 63;
    const int wave  = gt >> 6;
    const int which = wave & 1;
    const int h     = (wave >> 1) & (HH - 1);
    const int bl    = wave >> 5;

    float* p = qkv + (size_t)bl * (3 * CC) + which * CC + h * DD + lane;
    float v = *p;
    float ss = v * v;
#pragma unroll
    for (int off = 32; off; off >>= 1) ss += __shfl_xor(ss, off);
    float nrm = fmaxf(sqrtf(ss), 1e-12f);
    const float* g = which ? gk : gq;
    *p = v * (8.0f / nrm) * g[h * DD + lane];
}

__global__ __launch_bounds__(256)
void flash_fp32(float* __restrict__ qkv)
{
    const int qt = blockIdx.x, hh = blockIdx.y, bb = blockIdx.z;

    __shared__ float Qt[DD][64];
    __shared__ float Kt[DD][64];
    __shared__ float Vs[64][DD];
    __shared__ float Ps[64][64 + 4];

    const int tid = threadIdx.x;
    const int ty = tid >> 4, tx = tid & 15;
    const size_t rs_ = 3 * CC;
    const float* qbase = qkv + ((size_t)bb * LL + (size_t)qt * 64) * rs_ + hh * DD;
    const float* kbase = qkv + (size_t)bb * LL * rs_ + CC + hh * DD;
    const float* vbase = kbase + CC;

    {
        const int r = tid >> 2, c0 = (tid & 3) * 16;
#pragma unroll
        for (int u = 0; u < 4; ++u) {
            float4 v = *(const float4*)(qbase + (size_t)r * rs_ + c0 + u * 4);
            Qt[c0 + u*4 + 0][r] = v.x; Qt[c0 + u*4 + 1][r] = v.y;
            Qt[c0 + u*4 + 2][r] = v.z; Qt[c0 + u*4 + 3][r] = v.w;
        }
    }

    float mrow[4], lrow[4], O[4][4];
#pragma unroll
    for (int i = 0; i < 4; ++i) {
        mrow[i] = -INFINITY; lrow[i] = 0.f;
#pragma unroll
        for (int j = 0; j < 4; ++j) O[i][j] = 0.f;
    }

    for (int kt = 0; kt < LL / 64; ++kt) {
        __syncthreads();
        {
            const int r = tid >> 2, c0 = (tid & 3) * 16;
            const float* kr = kbase + ((size_t)kt * 64 + r) * rs_;
            const float* vr = vbase + ((size_t)kt * 64 + r) * rs_;
#pragma unroll
            for (int u = 0; u < 4; ++u) {
                float4 kv = *(const float4*)(kr + c0 + u * 4);
                Kt[c0 + u*4 + 0][r] = kv.x; Kt[c0 + u*4 + 1][r] = kv.y;
                Kt[c0 + u*4 + 2][r] = kv.z; Kt[c0 + u*4 + 3][r] = kv.w;
                *(float4*)&Vs[r][c0 + u*4] = *(const float4*)(vr + c0 + u * 4);
            }
        }
        __syncthreads();

        float S[4][4];
#pragma unroll
        for (int i = 0; i < 4; ++i)
#pragma unroll
            for (int j = 0; j < 4; ++j) S[i][j] = 0.f;
#pragma unroll 8
        for (int d = 0; d < DD; ++d) {
            float a[4], b[4];
            *(float4*)a = *(const float4*)&Qt[d][ty * 4];
            *(float4*)b = *(const float4*)&Kt[d][tx * 4];
#pragma unroll
            for (int i = 0; i < 4; ++i)
#pragma unroll
                for (int j = 0; j < 4; ++j) S[i][j] = fmaf(a[i], b[j], S[i][j]);
        }
#pragma unroll
        for (int i = 0; i < 4; ++i) {
#pragma unroll
            for (int j = 0; j < 4; ++j) S[i][j] *= 0.125f;
            float pm = fmaxf(fmaxf(S[i][0], S[i][1]), fmaxf(S[i][2], S[i][3]));
#pragma unroll
            for (int off = 1; off < 16; off <<= 1) pm = fmaxf(pm, __shfl_xor(pm, off));
            const float mnew = fmaxf(mrow[i], pm);
            const float corr = __expf(mrow[i] - mnew);
            float rsum = 0.f;
#pragma unroll
            for (int j = 0; j < 4; ++j) { S[i][j] = __expf(S[i][j] - mnew); rsum += S[i][j]; }
#pragma unroll
            for (int off = 1; off < 16; off <<= 1) rsum += __shfl_xor(rsum, off);
            mrow[i] = mnew;
            lrow[i] = lrow[i] * corr + rsum;
#pragma unroll
            for (int j = 0; j < 4; ++j) O[i][j] *= corr;
        }
#pragma unroll
        for (int i = 0; i < 4; ++i)
            *(float4*)&Ps[ty * 4 + i][tx * 4] = *(float4*)&S[i][0];
        __syncthreads();
#pragma unroll 4
        for (int k = 0; k < 64; k += 4) {
            float a[4][4];
#pragma unroll
            for (int i = 0; i < 4; ++i)
                *(float4*)&a[i][0] = *(const float4*)&Ps[ty * 4 + i][k];
#pragma unroll
            for (int kk = 0; kk < 4; ++kk) {
                float bv[4];
                *(float4*)bv = *(const float4*)&Vs[k + kk][tx * 4];
#pragma unroll
                for (int i = 0; i < 4; ++i)
#pragma unroll
                    for (int j = 0; j < 4; ++j)
                        O[i][j] = fmaf(a[i][kk], bv[j], O[i][j]);
            }
        }
    }

    float* obase = qkv + ((size_t)bb * LL + (size_t)qt * 64) * rs_ + hh * DD;
#pragma unroll
    for (int i = 0; i < 4; ++i) {
        const float inv = 1.f / lrow[i];
        float4 o;
        o.x = O[i][0] * inv; o.y = O[i][1] * inv;
        o.z = O[i][2] * inv; o.w = O[i][3] * inv;
        *(float4*)(obase + (size_t)(ty * 4 + i) * rs_ + tx * 4) = o;
    }
}

// ---------------------------------------------------------------------------
extern "C" void kernel_launch(void* const* d_in, const int* in_sizes, int n_in,
                              void* d_out, int out_size, void* d_ws, size_t ws_size,
                              hipStream_t stream)
{
    const float* x    = (const float*)d_in[0];
    const float* Wqkv = (const float*)d_in[1];
    const float* bqkv = (const float*)d_in[2];
    const float* gq   = (const float*)d_in[3];
    const float* gk   = (const float*)d_in[4];
    const float* Wout = (const float*)d_in[5];
    const float* bout = (const float*)d_in[6];
    float* out = (float*)d_out;

    const size_t NEED = 92274688ull; // 88 MiB (proven available)

    if (ws_size >= NEED) {
        char* wsb = (char*)d_ws;
        ushort_t* Qbh = (ushort_t*)(wsb);                 // 16 MiB
        ushort_t* Kh  = (ushort_t*)(wsb + 16777216);      // 16 MiB
        ushort_t* Vth = (ushort_t*)(wsb + 33554432);      // 16 MiB
        ushort_t* Hb  = (ushort_t*)(wsb + 50331648);      // 16 MiB
        ushort_t* wqh = (ushort_t*)(wsb + 67108864);      // 6 MiB
        ushort_t* woh = (ushort_t*)(wsb + 73400320);      // 2 MiB
        ushort_t* xh  = (ushort_t*)(wsb + 75497472);      // 16 MiB

        // one fused prep launch: x->bf16 (4096 blocks) + WqkvT (768) + WoutT (256)
        prep_all<<<dim3(4096 + 768 + 256), 256, 0, stream>>>(
            x, xh, Wqkv, wqh, Wout, woh);

        gemm_qkv<<<dim3(24 * 64), 256, 0, stream>>>(
            xh, wqh, bqkv, gq, gk, Qbh, Kh, Vth);

        flash13<<<dim3(512), 256, 0, stream>>>(Qbh, Kh, Vth, Hb);

        gemm_out1<<<dim3(8 * 64), 256, 0, stream>>>(Hb, woh, bout, out);
    } else {
        // legacy fp32 path
        float* qkv = (float*)d_ws;
        gemm_bias<<<dim3((3 * CC) / Bn, MM / Bb), 256, 0, stream>>>(
            x, Wqkv, bqkv, qkv, MM, 3 * CC, CC, CC, 3 * CC, 3 * CC);
        rmsnorm_qk<<<dim3((MM * HH * 2 * 64) / 256), 256, 0, stream>>>(qkv, gq, gk);
        flash_fp32<<<dim3(LL / 64, HH, BB), 256, 0, stream>>>(qkv);
        gemm_bias<<<dim3(CC / Bn, MM / Bb), 256, 0, stream>>>(
            qkv, Wout, bout, out, MM, CC, CC, 3 * CC, CC, CC);
    }
}

// Round 21
// 188.048 us; speedup vs baseline: 1.0083x; 1.0008x over previous
//
#include <hip/hip_runtime.h>
#include <math.h>

// Problem constants (B=4, L=2048, C=1024, H=16, D=64)
#define BB 4
#define LL 2048
#define CC 1024
#define HH 16
#define DD 64
#define MM (BB * LL) // 8192 rows

typedef float f32x4 __attribute__((ext_vector_type(4)));
typedef short short8 __attribute__((ext_vector_type(8))); // 8 bf16 (4 VGPRs)
typedef unsigned short ushort_t;
typedef unsigned long long u64_t;

#define MFMA_BF16(A, B, C) __builtin_amdgcn_mfma_f32_16x16x32_bf16(A, B, C, 0, 0, 0)

// q pre-scale: 1/sqrt(D) * log2(e), so softmax runs in exp2 domain
#define QSCALE 0.180336880f

__device__ __forceinline__ unsigned short f2bf(float x) {
    unsigned int u = __float_as_uint(x);
    u += 0x7fffu + ((u >> 16) & 1u); // RTN-even
    return (unsigned short)(u >> 16);
}

// pack two positive f32 into (bf16(b)<<16)|bf16(a), round-half-up via +0x8000
__device__ __forceinline__ unsigned pack_bf2(float a, float b) {
#if __has_builtin(__builtin_amdgcn_perm)
    return __builtin_amdgcn_perm(__float_as_uint(b) + 0x8000u,
                                 __float_as_uint(a) + 0x8000u, 0x07060302u);
#else
    return ((__float_as_uint(b) + 0x8000u) & 0xFFFF0000u) |
           ((__float_as_uint(a) + 0x8000u) >> 16);
#endif
}

// raw v_exp_f32 (domain here has no denormals; skip libm fixup)
__device__ __forceinline__ float fast_exp2(float x) {
#if __has_builtin(__builtin_amdgcn_exp2f)
    return __builtin_amdgcn_exp2f(x);
#else
    return exp2f(x);
#endif
}

// ---------------------------------------------------------------------------
// Fused prep: one launch.
//   blocks [0, 4096):        x f32 -> bf16 xh
//   blocks [4096, 4864):     Wqkv transpose+round -> wqh [3C][C]
//   blocks [4864, 5120):     Wout transpose+round -> woh [C][C]
// ---------------------------------------------------------------------------
__global__ __launch_bounds__(256)
void prep_all(const float* __restrict__ x, ushort_t* __restrict__ xh,
              const float* __restrict__ Wq, ushort_t* __restrict__ Tq,
              const float* __restrict__ Wo, ushort_t* __restrict__ To)
{
    __shared__ float sT[64][65];
    int bid = blockIdx.x;
    const int tid = threadIdx.x;

    if (bid < 4096) { // x rounding: 8 f32 per thread
        const int i = (bid * 256 + tid) * 8;
        f32x4 a = *(const f32x4*)(x + i);
        f32x4 b = *(const f32x4*)(x + i + 4);
        short8 h;
#pragma unroll
        for (int j = 0; j < 4; ++j) {
            h[j]     = (short)f2bf(a[j]);
            h[4 + j] = (short)f2bf(b[j]);
        }
        *(short8*)(xh + i) = h;
        return;
    }
    bid -= 4096;

    const float* W;
    ushort_t* T;
    int N, bx, by;
    if (bid < 768) { W = Wq; T = Tq; N = 3 * CC; bx = bid % 48; by = bid / 48; }
    else { bid -= 768; W = Wo; T = To; N = CC; bx = bid % 16; by = bid / 16; }

    const int K = CC;
    const int k0 = by * 64, n0 = bx * 64;
    const int r = tid >> 2, c0 = (tid & 3) * 16;

    const float* wp = W + (size_t)(k0 + r) * N + n0 + c0;
#pragma unroll
    for (int u = 0; u < 4; ++u) {
        f32x4 v = *(const f32x4*)(wp + 4 * u);
        sT[r][c0 + 4 * u + 0] = v[0];
        sT[r][c0 + 4 * u + 1] = v[1];
        sT[r][c0 + 4 * u + 2] = v[2];
        sT[r][c0 + 4 * u + 3] = v[3];
    }
    __syncthreads();

    const int nn = tid >> 2, kk0 = (tid & 3) * 16;
    short8 h0, h1;
#pragma unroll
    for (int u = 0; u < 8; ++u) {
        h0[u] = (short)f2bf(sT[kk0 + u][nn]);
        h1[u] = (short)f2bf(sT[kk0 + 8 + u][nn]);
    }
    ushort_t* oh = T + (size_t)(n0 + nn) * K + k0 + kk0;
    *(short8*)oh = h0; *(short8*)(oh + 8) = h1;
}

// ---------------------------------------------------------------------------
// Fused QKV GEMM, single-term bf16, next-K-tile register prefetch.
// Epilogue: rmsnorm q -> bf16 Qbh (xQSCALE), rmsnorm k -> bf16 Kh
// [b][h][l][d], v -> bf16 Vth transposed [b][h][d][l].
// ---------------------------------------------------------------------------
__global__ __launch_bounds__(256, 3)
void gemm_qkv(const ushort_t* __restrict__ Agh,
              const ushort_t* __restrict__ Bh,
              const float* __restrict__ bias,
              const float* __restrict__ gq, const float* __restrict__ gk,
              ushort_t* __restrict__ Qbh,
              ushort_t* __restrict__ Kh,
              ushort_t* __restrict__ Vth)
{
    __shared__ ushort_t smem[16384]; // 32 KB
    ushort_t* sAh = smem;
    ushort_t* sBh = smem + 8192;

    const int K = CC, lda = CC, nbx = (3 * CC) / 128; // 24

    const int nwg = gridDim.x;
    const int cpx = nwg >> 3;
    const int id  = blockIdx.x;
    const int swz = (id & 7) * cpx + (id >> 3);
    const int bx = swz % nbx, by = swz / nbx;
    const int m0 = by * 128, n0 = bx * 128;

    const int tid  = threadIdx.x;
    const int lane = tid & 63;
    const int wv   = tid >> 6;
    const int l4   = lane >> 4, l16 = lane & 15;
    const int wm   = wv >> 1,  wn  = wv & 1;

    const int r0  = tid >> 2;
    const int c0  = (tid & 3) * 16;
    const int ch0 = c0 >> 3;

    f32x4 acc[4][4];
#pragma unroll
    for (int i = 0; i < 4; ++i)
#pragma unroll
        for (int j = 0; j < 4; ++j) acc[i][j] = 0.f;

    short8 stgA[4], stgB[4];
#pragma unroll
    for (int it = 0; it < 2; ++it) {
        const ushort_t* ahp = Agh + (size_t)(m0 + r0 + 64 * it) * lda + c0;
        stgA[2 * it]     = *(const short8*)(ahp);
        stgA[2 * it + 1] = *(const short8*)(ahp + 8);
        const ushort_t* bhp = Bh + (size_t)(n0 + r0 + 64 * it) * K + c0;
        stgB[2 * it]     = *(const short8*)(bhp);
        stgB[2 * it + 1] = *(const short8*)(bhp + 8);
    }

    for (int kt = 0; kt < K; kt += 64) {
        __syncthreads();
#pragma unroll
        for (int it = 0; it < 2; ++it) {
            const int row  = r0 + 64 * it;
            const int sA   = row & 7;
            const int base = row * 64;
            const int cA = ((ch0) ^ sA) * 8, cB = ((ch0 + 1) ^ sA) * 8;
            *(short8*)&sAh[base + cA] = stgA[2 * it];
            *(short8*)&sAh[base + cB] = stgA[2 * it + 1];
            *(short8*)&sBh[base + cA] = stgB[2 * it];
            *(short8*)&sBh[base + cB] = stgB[2 * it + 1];
        }
        __syncthreads();

        if (kt + 64 < K) { // prefetch next K-tile (overlaps MFMA below)
#pragma unroll
            for (int it = 0; it < 2; ++it) {
                const ushort_t* ahp = Agh + (size_t)(m0 + r0 + 64 * it) * lda + kt + 64 + c0;
                stgA[2 * it]     = *(const short8*)(ahp);
                stgA[2 * it + 1] = *(const short8*)(ahp + 8);
                const ushort_t* bhp = Bh + (size_t)(n0 + r0 + 64 * it) * K + kt + 64 + c0;
                stgB[2 * it]     = *(const short8*)(bhp);
                stgB[2 * it + 1] = *(const short8*)(bhp + 8);
            }
        }

#pragma unroll
        for (int ks = 0; ks < 2; ++ks) {
            const int chf = (((ks << 2) | l4) ^ (l16 & 7)) * 8;
            short8 fbh[4];
#pragma unroll
            for (int j = 0; j < 4; ++j) {
                const int idx = (64 * wn + 16 * j + l16) * 64 + chf;
                fbh[j] = *(const short8*)&sBh[idx];
            }
#pragma unroll
            for (int i = 0; i < 4; ++i) {
                const int idx = (64 * wm + 16 * i + l16) * 64 + chf;
                short8 fah = *(const short8*)&sAh[idx];
#pragma unroll
                for (int j = 0; j < 4; ++j)
                    acc[i][j] = MFMA_BF16(fah, fbh[j], acc[i][j]);
            }
        }
    }

    // ---- epilogue -------------------------------------------------------
    const int region = n0 >> 10; // 0=q, 1=k, 2=v
    float bv[4];
#pragma unroll
    for (int j = 0; j < 4; ++j) bv[j] = bias[n0 + 64 * wn + 16 * j + l16];
#pragma unroll
    for (int i = 0; i < 4; ++i)
#pragma unroll
        for (int j = 0; j < 4; ++j)
#pragma unroll
            for (int r = 0; r < 4; ++r) acc[i][j][r] += bv[j];

    const int b = m0 >> 11;

    if (region < 2) {
        const int hloc = ((n0 & 1023) >> 6) + wn;
        const float* g = (region == 0 ? gq : gk) + hloc * DD;
        float gv[4];
#pragma unroll
        for (int j = 0; j < 4; ++j) gv[j] = g[16 * j + l16];
#pragma unroll
        for (int i = 0; i < 4; ++i)
#pragma unroll
        for (int r = 0; r < 4; ++r) {
            float ss = 0.f;
#pragma unroll
            for (int j = 0; j < 4; ++j) ss += acc[i][j][r] * acc[i][j][r];
#pragma unroll
            for (int off = 1; off < 16; off <<= 1) ss += __shfl_xor(ss, off);
            const float s = 8.0f / fmaxf(sqrtf(ss), 1e-12f);
#pragma unroll
            for (int j = 0; j < 4; ++j) acc[i][j][r] *= s * gv[j];
        }

        if (region == 0) {
            // q: bf16, pre-scaled for exp2-domain softmax
#pragma unroll
            for (int i = 0; i < 4; ++i)
#pragma unroll
            for (int r = 0; r < 4; ++r) {
                const int row = m0 + 64 * wm + 16 * i + 4 * l4 + r;
                ushort_t* op = Qbh + (size_t)row * CC + n0 + 64 * wn + l16;
#pragma unroll
                for (int j = 0; j < 4; ++j)
                    op[16 * j] = f2bf(acc[i][j][r] * QSCALE);
            }
        } else {
            const int hk = ((n0 - 1024) >> 6) + wn;
#pragma unroll
            for (int i = 0; i < 4; ++i)
#pragma unroll
            for (int r = 0; r < 4; ++r) {
                const int l = (m0 & 2047) + 64 * wm + 16 * i + 4 * l4 + r;
                const size_t base = ((size_t)(b * HH + hk) * LL + l) * DD + l16;
#pragma unroll
                for (int j = 0; j < 4; ++j)
                    Kh[base + 16 * j] = f2bf(acc[i][j][r]);
            }
        }
    } else {
        // V: bf16 + 128x128 LDS transpose + vector store to [b][h][d][l]
        __syncthreads();
        ushort_t* vh = smem; // [128][128] = 32 KB exactly
#pragma unroll
        for (int i = 0; i < 4; ++i)
#pragma unroll
        for (int r = 0; r < 4; ++r) {
            const int lr = 64 * wm + 16 * i + 4 * l4 + r;
#pragma unroll
            for (int j = 0; j < 4; ++j) {
                const int c = 64 * wn + 16 * j + l16;
                vh[lr * 128 + c] = f2bf(acc[i][j][r]);
            }
        }
        __syncthreads();
        const int c    = tid & 127;
        const int half = tid >> 7;
        const int hv   = ((n0 - 2048) >> 6) + (c >> 6);
        const int d    = c & 63;
        ushort_t* oh = Vth + ((size_t)(b * HH + hv) * DD + d) * LL + (m0 & 2047) + half * 64;
#pragma unroll
        for (int u = 0; u < 8; ++u) {
            const int l0 = half * 64 + u * 8;
            short8 hv8;
#pragma unroll
            for (int e = 0; e < 8; ++e)
                hv8[e] = (short)vh[(l0 + e) * 128 + c];
            *(short8*)&oh[u * 8] = hv8;
        }
    }
}

// ---------------------------------------------------------------------------
// Output projection, single-term bf16 with register prefetch.
// ---------------------------------------------------------------------------
__global__ __launch_bounds__(256, 3)
void gemm_out1(const ushort_t* __restrict__ Ah,
               const ushort_t* __restrict__ Bh,
               const float* __restrict__ bias, float* __restrict__ Cg)
{
    __shared__ ushort_t sAh[8192];
    __shared__ ushort_t sBh[8192];

    const int K = CC, nbx = CC / 128; // 8

    const int nwg = gridDim.x;
    const int cpx = nwg >> 3;
    const int id  = blockIdx.x;
    const int sw  = (id & 7) * cpx + (id >> 3);
    const int bx = sw % nbx, by = sw / nbx;
    const int m0 = by * 128, n0 = bx * 128;

    const int tid  = threadIdx.x;
    const int lane = tid & 63;
    const int wv   = tid >> 6;
    const int l4   = lane >> 4, l16 = lane & 15;
    const int wm   = wv >> 1,  wn  = wv & 1;

    const int r0  = tid >> 2;
    const int c0  = (tid & 3) * 16;
    const int ch0 = c0 >> 3;

    f32x4 acc[4][4];
#pragma unroll
    for (int i = 0; i < 4; ++i)
#pragma unroll
        for (int j = 0; j < 4; ++j) acc[i][j] = 0.f;

    short8 stgA[4], stgB[4];
#pragma unroll
    for (int it = 0; it < 2; ++it) {
        const ushort_t* ahp = Ah + (size_t)(m0 + r0 + 64 * it) * CC + c0;
        stgA[2 * it]     = *(const short8*)(ahp);
        stgA[2 * it + 1] = *(const short8*)(ahp + 8);
        const ushort_t* bhp = Bh + (size_t)(n0 + r0 + 64 * it) * K + c0;
        stgB[2 * it]     = *(const short8*)(bhp);
        stgB[2 * it + 1] = *(const short8*)(bhp + 8);
    }

    for (int kt = 0; kt < K; kt += 64) {
        __syncthreads();
#pragma unroll
        for (int it = 0; it < 2; ++it) {
            const int row  = r0 + 64 * it;
            const int sA   = row & 7;
            const int base = row * 64;
            const int cA = ((ch0) ^ sA) * 8, cB = ((ch0 + 1) ^ sA) * 8;
            *(short8*)&sAh[base + cA] = stgA[2 * it];
            *(short8*)&sAh[base + cB] = stgA[2 * it + 1];
            *(short8*)&sBh[base + cA] = stgB[2 * it];
            *(short8*)&sBh[base + cB] = stgB[2 * it + 1];
        }
        __syncthreads();

        if (kt + 64 < K) { // prefetch next K-tile
#pragma unroll
            for (int it = 0; it < 2; ++it) {
                const ushort_t* ahp = Ah + (size_t)(m0 + r0 + 64 * it) * CC + kt + 64 + c0;
                stgA[2 * it]     = *(const short8*)(ahp);
                stgA[2 * it + 1] = *(const short8*)(ahp + 8);
                const ushort_t* bhp = Bh + (size_t)(n0 + r0 + 64 * it) * K + kt + 64 + c0;
                stgB[2 * it]     = *(const short8*)(bhp);
                stgB[2 * it + 1] = *(const short8*)(bhp + 8);
            }
        }

#pragma unroll
        for (int ks = 0; ks < 2; ++ks) {
            const int chf = (((ks << 2) | l4) ^ (l16 & 7)) * 8;
            short8 fbh[4];
#pragma unroll
            for (int j = 0; j < 4; ++j) {
                const int idx = (64 * wn + 16 * j + l16) * 64 + chf;
                fbh[j] = *(const short8*)&sBh[idx];
            }
#pragma unroll
            for (int i = 0; i < 4; ++i) {
                const int idx = (64 * wm + 16 * i + l16) * 64 + chf;
                short8 fah = *(const short8*)&sAh[idx];
#pragma unroll
                for (int j = 0; j < 4; ++j)
                    acc[i][j] = MFMA_BF16(fah, fbh[j], acc[i][j]);
            }
        }
    }

    float bv[4];
#pragma unroll
    for (int j = 0; j < 4; ++j) bv[j] = bias[n0 + 64 * wn + 16 * j + l16];
#pragma unroll
    for (int i = 0; i < 4; ++i)
#pragma unroll
    for (int r = 0; r < 4; ++r) {
        const int row = m0 + 64 * wm + 16 * i + 4 * l4 + r;
        float* cp = Cg + (size_t)row * CC + n0 + 64 * wn + l16;
#pragma unroll
        for (int j = 0; j < 4; ++j) cp[16 * j] = acc[i][j][r] + bv[j];
    }
}

// ---------------------------------------------------------------------------
// Flash attention v13 = v11 (proven 87.4 us) + ping-pong staging registers:
// global loads for tile t+1 are issued BEFORE the ds_write of tile t
// (hiding window = ds_write + barrier + compute). Explicit even/odd unroll
// keeps all stg indexing compile-time constant (no scratch).
// QF=4 (64 q-rows/wave), fixed-shift exp2 softmax, KVBLK=64, zero conflicts,
// row-sum l via MFMA(P, ones).
// ---------------------------------------------------------------------------
__global__ __launch_bounds__(256, 2)
void flash13(const ushort_t* __restrict__ Qbh,
             const ushort_t* __restrict__ Kh,
             const ushort_t* __restrict__ Vth,
             ushort_t* __restrict__ Hb)
{
    __shared__ ushort_t sKh[4096], sVh[4096]; // 16 KB
    __shared__ ushort_t sP[4][64 * 68];       // 34 KB

    const int i    = blockIdx.x;          // 0..511
    const int xcd  = i & 7;
    const int slot = i >> 3;              // 0..63
    const int qt   = slot & 7;            // 8 q-tiles of 256 rows
    const int bh   = ((slot >> 3) << 3) | xcd;
    const int b    = bh >> 4, h = bh & 15;

    const int tid  = threadIdx.x;
    const int lane = tid & 63;
    const int wv   = tid >> 6;
    const int l4   = lane >> 4, l16 = lane & 15;

    // ---- Q fragments: 4 q-frags per wave (64 rows), pre-scaled bf16
    short8 qh[4][2];
    const int qr0 = qt * 256 + wv * 64;
#pragma unroll
    for (int qf = 0; qf < 4; ++qf)
#pragma unroll
    for (int sl = 0; sl < 2; ++sl)
        qh[qf][sl] = *(const short8*)(Qbh + (size_t)(b * LL + qr0 + qf * 16 + l16) * CC
                                      + h * DD + sl * 32 + l4 * 8);

    // bf16 1.0 vector for the MFMA row-sum
    short8 ones;
#pragma unroll
    for (int j = 0; j < 8; ++j) ones[j] = (short)0x3F80;

    f32x4 O[4][4];
    f32x4 acc_l[4];   // row-sum of P, layout q = 4*l4 + r (same as O rows)
#pragma unroll
    for (int qf = 0; qf < 4; ++qf) {
        acc_l[qf] = 0.f;
#pragma unroll
        for (int t = 0; t < 4; ++t) O[qf][t] = 0.f;
    }

    const int r_ = tid >> 2;          // staging row 0..63
    const int c2 = (tid & 3) * 2;     // chunk pair
    const size_t kgb0 = ((size_t)bh * LL + r_) * DD + c2 * 8;
    const size_t vgb0 = ((size_t)bh * DD + r_) * LL + c2 * 8;

    short8 stgA[4], stgB[4];
    // tile 0 -> stgA
    stgA[0] = *(const short8*)&Kh[kgb0];      stgA[1] = *(const short8*)&Kh[kgb0 + 8];
    stgA[2] = *(const short8*)&Vth[vgb0];     stgA[3] = *(const short8*)&Vth[vgb0 + 8];

    // one KV-tile step: cur holds tile kt (to be written to LDS), nxt gets
    // the loads for tile kt+1 issued BEFORE the ds_write of cur.
#define FLASH_STEP(cur, nxt, kt)                                               \
    {                                                                          \
        __syncthreads(); /* previous tile fully consumed */                    \
        if ((kt) + 1 < LL / 64) { /* issue next-tile loads early */            \
            const size_t kgb = kgb0 + (size_t)((kt) + 1) * 64 * DD;            \
            const size_t vgb = vgb0 + (size_t)((kt) + 1) * 64;                 \
            nxt[0] = *(const short8*)&Kh[kgb];                                 \
            nxt[1] = *(const short8*)&Kh[kgb + 8];                             \
            nxt[2] = *(const short8*)&Vth[vgb];                                \
            nxt[3] = *(const short8*)&Vth[vgb + 8];                            \
        }                                                                      \
        {                                                                      \
            const int wr = r_ * 64, s = r_ & 7;                                \
            const int cA = ((c2) ^ s) * 8, cB = ((c2 + 1) ^ s) * 8;            \
            *(short8*)&sKh[wr + cA] = cur[0];                                  \
            *(short8*)&sKh[wr + cB] = cur[1];                                  \
            *(short8*)&sVh[wr + cA] = cur[2];                                  \
            *(short8*)&sVh[wr + cB] = cur[3];                                  \
        }                                                                      \
        __syncthreads();                                                       \
        f32x4 S[4][4];                                                         \
        _Pragma("unroll")                                                      \
        for (int qf = 0; qf < 4; ++qf)                                         \
            _Pragma("unroll")                                                  \
            for (int t = 0; t < 4; ++t) S[qf][t] = 0.f;                        \
        __builtin_amdgcn_s_setprio(1);                                         \
        _Pragma("unroll")                                                      \
        for (int t = 0; t < 4; ++t) {                                          \
            const int row = 16 * t + l16;                                      \
            const int swr = row & 7;                                           \
            _Pragma("unroll")                                                  \
            for (int sl = 0; sl < 2; ++sl) {                                   \
                const int idx = row * 64 + (((sl << 2) | l4) ^ swr) * 8;       \
                short8 kh8 = *(const short8*)&sKh[idx];                        \
                _Pragma("unroll")                                              \
                for (int qf = 0; qf < 4; ++qf)                                 \
                    S[qf][t] = MFMA_BF16(kh8, qh[qf][sl], S[qf][t]);           \
            }                                                                  \
        }                                                                      \
        __builtin_amdgcn_s_setprio(0);                                         \
        _Pragma("unroll")                                                      \
        for (int qf = 0; qf < 4; ++qf)                                         \
            _Pragma("unroll")                                                  \
            for (int t = 0; t < 4; ++t)                                        \
                _Pragma("unroll")                                              \
                for (int r = 0; r < 4; ++r)                                    \
                    S[qf][t][r] = fast_exp2(S[qf][t][r]);                      \
        _Pragma("unroll")                                                      \
        for (int qf = 0; qf < 4; ++qf)                                         \
            _Pragma("unroll")                                                  \
            for (int t = 0; t < 4; ++t) {                                      \
                unsigned lo = pack_bf2(S[qf][t][0], S[qf][t][1]);              \
                unsigned hi = pack_bf2(S[qf][t][2], S[qf][t][3]);              \
                const int widx = (qf * 16 + l16) * 68 + 16 * t + 4 * l4;       \
                *(u64_t*)&sP[wv][widx] = (u64_t)lo | ((u64_t)hi << 32);        \
            }                                                                  \
        asm volatile("s_waitcnt lgkmcnt(0)" ::: "memory");                     \
        __builtin_amdgcn_sched_barrier(0);                                     \
        short8 pa[4][2];                                                       \
        _Pragma("unroll")                                                      \
        for (int qf = 0; qf < 4; ++qf)                                         \
            _Pragma("unroll")                                                  \
            for (int sl = 0; sl < 2; ++sl) {                                   \
                const int ridx = (qf * 16 + l16) * 68 + sl * 32 + 8 * l4;      \
                union { u64_t q[2]; short8 s8; } u;                            \
                u.q[0] = *(const u64_t*)&sP[wv][ridx];                         \
                u.q[1] = *(const u64_t*)&sP[wv][ridx + 4];                     \
                pa[qf][sl] = u.s8;                                             \
            }                                                                  \
        __builtin_amdgcn_s_setprio(1);                                         \
        _Pragma("unroll")                                                      \
        for (int qf = 0; qf < 4; ++qf) {                                       \
            acc_l[qf] = MFMA_BF16(pa[qf][0], ones, acc_l[qf]);                 \
            acc_l[qf] = MFMA_BF16(pa[qf][1], ones, acc_l[qf]);                 \
        }                                                                      \
        _Pragma("unroll")                                                      \
        for (int dt = 0; dt < 4; ++dt) {                                       \
            const int row = 16 * dt + l16;                                     \
            const int swr = row & 7;                                           \
            _Pragma("unroll")                                                  \
            for (int sl = 0; sl < 2; ++sl) {                                   \
                const int idx = row * 64 + (((sl << 2) | l4) ^ swr) * 8;       \
                short8 vh8 = *(const short8*)&sVh[idx];                        \
                _Pragma("unroll")                                              \
                for (int qf = 0; qf < 4; ++qf)                                 \
                    O[qf][dt] = MFMA_BF16(pa[qf][sl], vh8, O[qf][dt]);         \
            }                                                                  \
        }                                                                      \
        __builtin_amdgcn_s_setprio(0);                                         \
    }

    for (int kt = 0; kt < LL / 64; kt += 2) {
        FLASH_STEP(stgA, stgB, kt);
        FLASH_STEP(stgB, stgA, kt + 1);
    }
#undef FLASH_STEP

    // ---- epilogue: h = O / l -> bf16 Hb rows (l is lane-local)
#pragma unroll
    for (int qf = 0; qf < 4; ++qf) {
        f32x4 iv;
#pragma unroll
        for (int r = 0; r < 4; ++r) iv[r] = 1.0f / acc_l[qf][r];
#pragma unroll
        for (int r = 0; r < 4; ++r) {
            const int q = qr0 + qf * 16 + 4 * l4 + r;
            ushort_t* op = Hb + (size_t)(b * LL + q) * CC + h * DD + l16;
#pragma unroll
            for (int dt = 0; dt < 4; ++dt)
                op[16 * dt] = f2bf(O[qf][dt][r] * iv[r]);
        }
    }
}

// ---------------------------------------------------------------------------
// Legacy fp32 fallback kernels (only if ws_size is too small; never expected)
// ---------------------------------------------------------------------------
#define Bb 128
#define Bn 128
#define BKG 8

__global__ __launch_bounds__(256)
void gemm_bias(const float* __restrict__ A, const float* __restrict__ B,
               const float* __restrict__ bias, float* __restrict__ C,
               int M, int N, int K, int lda, int ldb, int ldc)
{
    __shared__ float As[BKG][Bb];
    __shared__ float Bs[BKG][Bn];

    const int tid = threadIdx.x;
    const int m0 = blockIdx.y * Bb;
    const int n0 = blockIdx.x * Bn;
    const int ty = tid >> 4, tx = tid & 15;
    const int arow = tid >> 1, acol = (tid & 1) * 4;
    const int brow = tid >> 5, bcol = (tid & 31) * 4;

    const float* Ap = A + (size_t)(m0 + arow) * lda + acol;
    const float* Bp = B + (size_t)brow * ldb + n0 + bcol;

    float acc[8][8];
#pragma unroll
    for (int i = 0; i < 8; ++i)
#pragma unroll
        for (int j = 0; j < 8; ++j) acc[i][j] = 0.f;

    for (int k0 = 0; k0 < K; k0 += BKG) {
        float4 av = *(const float4*)(Ap + k0);
        float4 bv = *(const float4*)(Bp + (size_t)k0 * ldb);
        __syncthreads();
        As[acol + 0][arow] = av.x;
        As[acol + 1][arow] = av.y;
        As[acol + 2][arow] = av.z;
        As[acol + 3][arow] = av.w;
        *(float4*)&Bs[brow][bcol] = bv;
        __syncthreads();
#pragma unroll
        for (int kk = 0; kk < BKG; ++kk) {
            float a[8], bvv[8];
            *(float4*)&a[0] = *(const float4*)&As[kk][ty * 4];
            *(float4*)&a[4] = *(const float4*)&As[kk][64 + ty * 4];
            *(float4*)&bvv[0] = *(const float4*)&Bs[kk][tx * 4];
            *(float4*)&bvv[4] = *(const float4*)&Bs[kk][64 + tx * 4];
#pragma unroll
            for (int i = 0; i < 8; ++i)
#pragma unroll
                for (int j = 0; j < 8; ++j)
                    acc[i][j] = fmaf(a[i], bvv[j], acc[i][j]);
        }
    }
#pragma unroll
    for (int ih = 0; ih < 2; ++ih)
#pragma unroll
    for (int i = 0; i < 4; ++i) {
        const int m = m0 + ih * 64 + ty * 4 + i;
#pragma unroll
        for (int jh = 0; jh < 2; ++jh) {
            const int n = n0 + jh * 64 + tx * 4;
            float4 o;
            o.x = acc[ih*4+i][jh*4+0] + bias[n+0];
            o.y = acc[ih*4+i][jh*4+1] + bias[n+1];
            o.z = acc[ih*4+i][jh*4+2] + bias[n+2];
            o.w = acc[ih*4+i][jh*4+3] + bias[n+3];
            *(float4*)(C + (size_t)m * ldc + n) = o;
        }
    }
}

__global__ __launch_bounds__(256)
void rmsnorm_qk(float* __restrict__ qkv,
                const float* __restrict__ gq, const float* __restrict__ gk)
{
    const int gt    = blockIdx.x * 256 + threadIdx.x;
    const int lane  = gt & 63;
    const int wave  = gt >> 6;
    const int which = wave & 1;
    const int h     = (wave >> 1) & (HH - 1);
    const int bl    = wave >> 5;

    float* p = qkv + (size_t)bl * (3 * CC) + which * CC + h * DD + lane;
    float v = *p;
    float ss = v * v;
#pragma unroll
    for (int off = 32; off; off >>= 1) ss += __shfl_xor(ss, off);
    float nrm = fmaxf(sqrtf(ss), 1e-12f);
    const float* g = which ? gk : gq;
    *p = v * (8.0f / nrm) * g[h * DD + lane];
}

__global__ __launch_bounds__(256)
void flash_fp32(float* __restrict__ qkv)
{
    const int qt = blockIdx.x, hh = blockIdx.y, bb = blockIdx.z;

    __shared__ float Qt[DD][64];
    __shared__ float Kt[DD][64];
    __shared__ float Vs[64][DD];
    __shared__ float Ps[64][64 + 4];

    const int tid = threadIdx.x;
    const int ty = tid >> 4, tx = tid & 15;
    const size_t rs_ = 3 * CC;
    const float* qbase = qkv + ((size_t)bb * LL + (size_t)qt * 64) * rs_ + hh * DD;
    const float* kbase = qkv + (size_t)bb * LL * rs_ + CC + hh * DD;
    const float* vbase = kbase + CC;

    {
        const int r = tid >> 2, c0 = (tid & 3) * 16;
#pragma unroll
        for (int u = 0; u < 4; ++u) {
            float4 v = *(const float4*)(qbase + (size_t)r * rs_ + c0 + u * 4);
            Qt[c0 + u*4 + 0][r] = v.x; Qt[c0 + u*4 + 1][r] = v.y;
            Qt[c0 + u*4 + 2][r] = v.z; Qt[c0 + u*4 + 3][r] = v.w;
        }
    }

    float mrow[4], lrow[4], O[4][4];
#pragma unroll
    for (int i = 0; i < 4; ++i) {
        mrow[i] = -INFINITY; lrow[i] = 0.f;
#pragma unroll
        for (int j = 0; j < 4; ++j) O[i][j] = 0.f;
    }

    for (int kt = 0; kt < LL / 64; ++kt) {
        __syncthreads();
        {
            const int r = tid >> 2, c0 = (tid & 3) * 16;
            const float* kr = kbase + ((size_t)kt * 64 + r) * rs_;
            const float* vr = vbase + ((size_t)kt * 64 + r) * rs_;
#pragma unroll
            for (int u = 0; u < 4; ++u) {
                float4 kv = *(const float4*)(kr + c0 + u * 4);
                Kt[c0 + u*4 + 0][r] = kv.x; Kt[c0 + u*4 + 1][r] = kv.y;
                Kt[c0 + u*4 + 2][r] = kv.z; Kt[c0 + u*4 + 3][r] = kv.w;
                *(float4*)&Vs[r][c0 + u*4] = *(const float4*)(vr + c0 + u * 4);
            }
        }
        __syncthreads();

        float S[4][4];
#pragma unroll
        for (int i = 0; i < 4; ++i)
#pragma unroll
            for (int j = 0; j < 4; ++j) S[i][j] = 0.f;
#pragma unroll 8
        for (int d = 0; d < DD; ++d) {
            float a[4], b[4];
            *(float4*)a = *(const float4*)&Qt[d][ty * 4];
            *(float4*)b = *(const float4*)&Kt[d][tx * 4];
#pragma unroll
            for (int i = 0; i < 4; ++i)
#pragma unroll
                for (int j = 0; j < 4; ++j) S[i][j] = fmaf(a[i], b[j], S[i][j]);
        }
#pragma unroll
        for (int i = 0; i < 4; ++i) {
#pragma unroll
            for (int j = 0; j < 4; ++j) S[i][j] *= 0.125f;
            float pm = fmaxf(fmaxf(S[i][0], S[i][1]), fmaxf(S[i][2], S[i][3]));
#pragma unroll
            for (int off = 1; off < 16; off <<= 1) pm = fmaxf(pm, __shfl_xor(pm, off));
            const float mnew = fmaxf(mrow[i], pm);
            const float corr = __expf(mrow[i] - mnew);
            float rsum = 0.f;
#pragma unroll
            for (int j = 0; j < 4; ++j) { S[i][j] = __expf(S[i][j] - mnew); rsum += S[i][j]; }
#pragma unroll
            for (int off = 1; off < 16; off <<= 1) rsum += __shfl_xor(rsum, off);
            mrow[i] = mnew;
            lrow[i] = lrow[i] * corr + rsum;
#pragma unroll
            for (int j = 0; j < 4; ++j) O[i][j] *= corr;
        }
#pragma unroll
        for (int i = 0; i < 4; ++i)
            *(float4*)&Ps[ty * 4 + i][tx * 4] = *(float4*)&S[i][0];
        __syncthreads();
#pragma unroll 4
        for (int k = 0; k < 64; k += 4) {
            float a[4][4];
#pragma unroll
            for (int i = 0; i < 4; ++i)
                *(float4*)&a[i][0] = *(const float4*)&Ps[ty * 4 + i][k];
#pragma unroll
            for (int kk = 0; kk < 4; ++kk) {
                float bv[4];
                *(float4*)bv = *(const float4*)&Vs[k + kk][tx * 4];
#pragma unroll
                for (int i = 0; i < 4; ++i)
#pragma unroll
                    for (int j = 0; j < 4; ++j)
                        O[i][j] = fmaf(a[i][kk], bv[j], O[i][j]);
            }
        }
    }

    float* obase = qkv + ((size_t)bb * LL + (size_t)qt * 64) * rs_ + hh * DD;
#pragma unroll
    for (int i = 0; i < 4; ++i) {
        const float inv = 1.f / lrow[i];
        float4 o;
        o.x = O[i][0] * inv; o.y = O[i][1] * inv;
        o.z = O[i][2] * inv; o.w = O[i][3] * inv;
        *(float4*)(obase + (size_t)(ty * 4 + i) * rs_ + tx * 4) = o;
    }
}

// ---------------------------------------------------------------------------
extern "C" void kernel_launch(void* const* d_in, const int* in_sizes, int n_in,
                              void* d_out, int out_size, void* d_ws, size_t ws_size,
                              hipStream_t stream)
{
    const float* x    = (const float*)d_in[0];
    const float* Wqkv = (const float*)d_in[1];
    const float* bqkv = (const float*)d_in[2];
    const float* gq   = (const float*)d_in[3];
    const float* gk   = (const float*)d_in[4];
    const float* Wout = (const float*)d_in[5];
    const float* bout = (const float*)d_in[6];
    float* out = (float*)d_out;

    const size_t NEED = 92274688ull; // 88 MiB (proven available)

    if (ws_size >= NEED) {
        char* wsb = (char*)d_ws;
        ushort_t* Qbh = (ushort_t*)(wsb);                 // 16 MiB
        ushort_t* Kh  = (ushort_t*)(wsb + 16777216);      // 16 MiB
        ushort_t* Vth = (ushort_t*)(wsb + 33554432);      // 16 MiB
        ushort_t* Hb  = (ushort_t*)(wsb + 50331648);      // 16 MiB
        ushort_t* wqh = (ushort_t*)(wsb + 67108864);      // 6 MiB
        ushort_t* woh = (ushort_t*)(wsb + 73400320);      // 2 MiB
        ushort_t* xh  = (ushort_t*)(wsb + 75497472);      // 16 MiB

        // one fused prep launch: x->bf16 (4096 blocks) + WqkvT (768) + WoutT (256)
        prep_all<<<dim3(4096 + 768 + 256), 256, 0, stream>>>(
            x, xh, Wqkv, wqh, Wout, woh);

        gemm_qkv<<<dim3(24 * 64), 256, 0, stream>>>(
            xh, wqh, bqkv, gq, gk, Qbh, Kh, Vth);

        flash13<<<dim3(512), 256, 0, stream>>>(Qbh, Kh, Vth, Hb);

        gemm_out1<<<dim3(8 * 64), 256, 0, stream>>>(Hb, woh, bout, out);
    } else {
        // legacy fp32 path
        float* qkv = (float*)d_ws;
        gemm_bias<<<dim3((3 * CC) / Bn, MM / Bb), 256, 0, stream>>>(
            x, Wqkv, bqkv, qkv, MM, 3 * CC, CC, CC, 3 * CC, 3 * CC);
        rmsnorm_qk<<<dim3((MM * HH * 2 * 64) / 256), 256, 0, stream>>>(qkv, gq, gk);
        flash_fp32<<<dim3(LL / 64, HH, BB), 256, 0, stream>>>(qkv);
        gemm_bias<<<dim3(CC / Bn, MM / Bb), 256, 0, stream>>>(
            qkv, Wout, bout, out, MM, CC, CC, 3 * CC, CC, CC);
    }
}

// Round 22
// 185.645 us; speedup vs baseline: 1.0214x; 1.0129x over previous
//
#include <hip/hip_runtime.h>
#include <math.h>

// Problem constants (B=4, L=2048, C=1024, H=16, D=64)
#define BB 4
#define LL 2048
#define CC 1024
#define HH 16
#define DD 64
#define MM (BB * LL) // 8192 rows

typedef float f32x4 __attribute__((ext_vector_type(4)));
typedef short short8 __attribute__((ext_vector_type(8))); // 8 bf16 (4 VGPRs)
typedef unsigned short ushort_t;
typedef unsigned long long u64_t;

#define MFMA_BF16(A, B, C) __builtin_amdgcn_mfma_f32_16x16x32_bf16(A, B, C, 0, 0, 0)

// q pre-scale: 1/sqrt(D) * log2(e), so softmax runs in exp2 domain
#define QSCALE 0.180336880f

__device__ __forceinline__ unsigned short f2bf(float x) {
    unsigned int u = __float_as_uint(x);
    u += 0x7fffu + ((u >> 16) & 1u); // RTN-even
    return (unsigned short)(u >> 16);
}

// pack two positive f32 into (bf16(b)<<16)|bf16(a), round-half-up via +0x8000
__device__ __forceinline__ unsigned pack_bf2(float a, float b) {
#if __has_builtin(__builtin_amdgcn_perm)
    return __builtin_amdgcn_perm(__float_as_uint(b) + 0x8000u,
                                 __float_as_uint(a) + 0x8000u, 0x07060302u);
#else
    return ((__float_as_uint(b) + 0x8000u) & 0xFFFF0000u) |
           ((__float_as_uint(a) + 0x8000u) >> 16);
#endif
}

// raw v_exp_f32 (domain here has no denormals; skip libm fixup)
__device__ __forceinline__ float fast_exp2(float x) {
#if __has_builtin(__builtin_amdgcn_exp2f)
    return __builtin_amdgcn_exp2f(x);
#else
    return exp2f(x);
#endif
}

// ---------------------------------------------------------------------------
// Fused prep: one launch.
//   blocks [0, 4096):        x f32 -> bf16 xh
//   blocks [4096, 4864):     Wqkv transpose+round -> wqh [3C][C]
//   blocks [4864, 5120):     Wout transpose+round -> woh [C][C]
// ---------------------------------------------------------------------------
__global__ __launch_bounds__(256)
void prep_all(const float* __restrict__ x, ushort_t* __restrict__ xh,
              const float* __restrict__ Wq, ushort_t* __restrict__ Tq,
              const float* __restrict__ Wo, ushort_t* __restrict__ To)
{
    __shared__ float sT[64][65];
    int bid = blockIdx.x;
    const int tid = threadIdx.x;

    if (bid < 4096) { // x rounding: 8 f32 per thread
        const int i = (bid * 256 + tid) * 8;
        f32x4 a = *(const f32x4*)(x + i);
        f32x4 b = *(const f32x4*)(x + i + 4);
        short8 h;
#pragma unroll
        for (int j = 0; j < 4; ++j) {
            h[j]     = (short)f2bf(a[j]);
            h[4 + j] = (short)f2bf(b[j]);
        }
        *(short8*)(xh + i) = h;
        return;
    }
    bid -= 4096;

    const float* W;
    ushort_t* T;
    int N, bx, by;
    if (bid < 768) { W = Wq; T = Tq; N = 3 * CC; bx = bid % 48; by = bid / 48; }
    else { bid -= 768; W = Wo; T = To; N = CC; bx = bid % 16; by = bid / 16; }

    const int K = CC;
    const int k0 = by * 64, n0 = bx * 64;
    const int r = tid >> 2, c0 = (tid & 3) * 16;

    const float* wp = W + (size_t)(k0 + r) * N + n0 + c0;
#pragma unroll
    for (int u = 0; u < 4; ++u) {
        f32x4 v = *(const f32x4*)(wp + 4 * u);
        sT[r][c0 + 4 * u + 0] = v[0];
        sT[r][c0 + 4 * u + 1] = v[1];
        sT[r][c0 + 4 * u + 2] = v[2];
        sT[r][c0 + 4 * u + 3] = v[3];
    }
    __syncthreads();

    const int nn = tid >> 2, kk0 = (tid & 3) * 16;
    short8 h0, h1;
#pragma unroll
    for (int u = 0; u < 8; ++u) {
        h0[u] = (short)f2bf(sT[kk0 + u][nn]);
        h1[u] = (short)f2bf(sT[kk0 + 8 + u][nn]);
    }
    ushort_t* oh = T + (size_t)(n0 + nn) * K + k0 + kk0;
    *(short8*)oh = h0; *(short8*)(oh + 8) = h1;
}

// ---------------------------------------------------------------------------
// Fused QKV GEMM, single-term bf16, next-K-tile register prefetch.
// Epilogue: rmsnorm q -> bf16 Qbh (xQSCALE), rmsnorm k -> bf16 Kh
// [b][h][l][d], v -> bf16 Vth transposed [b][h][d][l].
// ---------------------------------------------------------------------------
__global__ __launch_bounds__(256, 3)
void gemm_qkv(const ushort_t* __restrict__ Agh,
              const ushort_t* __restrict__ Bh,
              const float* __restrict__ bias,
              const float* __restrict__ gq, const float* __restrict__ gk,
              ushort_t* __restrict__ Qbh,
              ushort_t* __restrict__ Kh,
              ushort_t* __restrict__ Vth)
{
    __shared__ ushort_t smem[16384]; // 32 KB
    ushort_t* sAh = smem;
    ushort_t* sBh = smem + 8192;

    const int K = CC, lda = CC, nbx = (3 * CC) / 128; // 24

    const int nwg = gridDim.x;
    const int cpx = nwg >> 3;
    const int id  = blockIdx.x;
    const int swz = (id & 7) * cpx + (id >> 3);
    const int bx = swz % nbx, by = swz / nbx;
    const int m0 = by * 128, n0 = bx * 128;

    const int tid  = threadIdx.x;
    const int lane = tid & 63;
    const int wv   = tid >> 6;
    const int l4   = lane >> 4, l16 = lane & 15;
    const int wm   = wv >> 1,  wn  = wv & 1;

    const int r0  = tid >> 2;
    const int c0  = (tid & 3) * 16;
    const int ch0 = c0 >> 3;

    f32x4 acc[4][4];
#pragma unroll
    for (int i = 0; i < 4; ++i)
#pragma unroll
        for (int j = 0; j < 4; ++j) acc[i][j] = 0.f;

    short8 stgA[4], stgB[4];
#pragma unroll
    for (int it = 0; it < 2; ++it) {
        const ushort_t* ahp = Agh + (size_t)(m0 + r0 + 64 * it) * lda + c0;
        stgA[2 * it]     = *(const short8*)(ahp);
        stgA[2 * it + 1] = *(const short8*)(ahp + 8);
        const ushort_t* bhp = Bh + (size_t)(n0 + r0 + 64 * it) * K + c0;
        stgB[2 * it]     = *(const short8*)(bhp);
        stgB[2 * it + 1] = *(const short8*)(bhp + 8);
    }

    for (int kt = 0; kt < K; kt += 64) {
        __syncthreads();
#pragma unroll
        for (int it = 0; it < 2; ++it) {
            const int row  = r0 + 64 * it;
            const int sA   = row & 7;
            const int base = row * 64;
            const int cA = ((ch0) ^ sA) * 8, cB = ((ch0 + 1) ^ sA) * 8;
            *(short8*)&sAh[base + cA] = stgA[2 * it];
            *(short8*)&sAh[base + cB] = stgA[2 * it + 1];
            *(short8*)&sBh[base + cA] = stgB[2 * it];
            *(short8*)&sBh[base + cB] = stgB[2 * it + 1];
        }
        __syncthreads();

        if (kt + 64 < K) { // prefetch next K-tile (overlaps MFMA below)
#pragma unroll
            for (int it = 0; it < 2; ++it) {
                const ushort_t* ahp = Agh + (size_t)(m0 + r0 + 64 * it) * lda + kt + 64 + c0;
                stgA[2 * it]     = *(const short8*)(ahp);
                stgA[2 * it + 1] = *(const short8*)(ahp + 8);
                const ushort_t* bhp = Bh + (size_t)(n0 + r0 + 64 * it) * K + kt + 64 + c0;
                stgB[2 * it]     = *(const short8*)(bhp);
                stgB[2 * it + 1] = *(const short8*)(bhp + 8);
            }
        }

#pragma unroll
        for (int ks = 0; ks < 2; ++ks) {
            const int chf = (((ks << 2) | l4) ^ (l16 & 7)) * 8;
            short8 fbh[4];
#pragma unroll
            for (int j = 0; j < 4; ++j) {
                const int idx = (64 * wn + 16 * j + l16) * 64 + chf;
                fbh[j] = *(const short8*)&sBh[idx];
            }
#pragma unroll
            for (int i = 0; i < 4; ++i) {
                const int idx = (64 * wm + 16 * i + l16) * 64 + chf;
                short8 fah = *(const short8*)&sAh[idx];
#pragma unroll
                for (int j = 0; j < 4; ++j)
                    acc[i][j] = MFMA_BF16(fah, fbh[j], acc[i][j]);
            }
        }
    }

    // ---- epilogue -------------------------------------------------------
    const int region = n0 >> 10; // 0=q, 1=k, 2=v
    float bv[4];
#pragma unroll
    for (int j = 0; j < 4; ++j) bv[j] = bias[n0 + 64 * wn + 16 * j + l16];
#pragma unroll
    for (int i = 0; i < 4; ++i)
#pragma unroll
        for (int j = 0; j < 4; ++j)
#pragma unroll
            for (int r = 0; r < 4; ++r) acc[i][j][r] += bv[j];

    const int b = m0 >> 11;

    if (region < 2) {
        const int hloc = ((n0 & 1023) >> 6) + wn;
        const float* g = (region == 0 ? gq : gk) + hloc * DD;
        float gv[4];
#pragma unroll
        for (int j = 0; j < 4; ++j) gv[j] = g[16 * j + l16];
#pragma unroll
        for (int i = 0; i < 4; ++i)
#pragma unroll
        for (int r = 0; r < 4; ++r) {
            float ss = 0.f;
#pragma unroll
            for (int j = 0; j < 4; ++j) ss += acc[i][j][r] * acc[i][j][r];
#pragma unroll
            for (int off = 1; off < 16; off <<= 1) ss += __shfl_xor(ss, off);
            const float s = 8.0f / fmaxf(sqrtf(ss), 1e-12f);
#pragma unroll
            for (int j = 0; j < 4; ++j) acc[i][j][r] *= s * gv[j];
        }

        if (region == 0) {
            // q: bf16, pre-scaled for exp2-domain softmax
#pragma unroll
            for (int i = 0; i < 4; ++i)
#pragma unroll
            for (int r = 0; r < 4; ++r) {
                const int row = m0 + 64 * wm + 16 * i + 4 * l4 + r;
                ushort_t* op = Qbh + (size_t)row * CC + n0 + 64 * wn + l16;
#pragma unroll
                for (int j = 0; j < 4; ++j)
                    op[16 * j] = f2bf(acc[i][j][r] * QSCALE);
            }
        } else {
            const int hk = ((n0 - 1024) >> 6) + wn;
#pragma unroll
            for (int i = 0; i < 4; ++i)
#pragma unroll
            for (int r = 0; r < 4; ++r) {
                const int l = (m0 & 2047) + 64 * wm + 16 * i + 4 * l4 + r;
                const size_t base = ((size_t)(b * HH + hk) * LL + l) * DD + l16;
#pragma unroll
                for (int j = 0; j < 4; ++j)
                    Kh[base + 16 * j] = f2bf(acc[i][j][r]);
            }
        }
    } else {
        // V: bf16 + 128x128 LDS transpose + vector store to [b][h][d][l]
        __syncthreads();
        ushort_t* vh = smem; // [128][128] = 32 KB exactly
#pragma unroll
        for (int i = 0; i < 4; ++i)
#pragma unroll
        for (int r = 0; r < 4; ++r) {
            const int lr = 64 * wm + 16 * i + 4 * l4 + r;
#pragma unroll
            for (int j = 0; j < 4; ++j) {
                const int c = 64 * wn + 16 * j + l16;
                vh[lr * 128 + c] = f2bf(acc[i][j][r]);
            }
        }
        __syncthreads();
        const int c    = tid & 127;
        const int half = tid >> 7;
        const int hv   = ((n0 - 2048) >> 6) + (c >> 6);
        const int d    = c & 63;
        ushort_t* oh = Vth + ((size_t)(b * HH + hv) * DD + d) * LL + (m0 & 2047) + half * 64;
#pragma unroll
        for (int u = 0; u < 8; ++u) {
            const int l0 = half * 64 + u * 8;
            short8 hv8;
#pragma unroll
            for (int e = 0; e < 8; ++e)
                hv8[e] = (short)vh[(l0 + e) * 128 + c];
            *(short8*)&oh[u * 8] = hv8;
        }
    }
}

// ---------------------------------------------------------------------------
// Output projection, single-term bf16 with register prefetch.
// ---------------------------------------------------------------------------
__global__ __launch_bounds__(256, 3)
void gemm_out1(const ushort_t* __restrict__ Ah,
               const ushort_t* __restrict__ Bh,
               const float* __restrict__ bias, float* __restrict__ Cg)
{
    __shared__ ushort_t sAh[8192];
    __shared__ ushort_t sBh[8192];

    const int K = CC, nbx = CC / 128; // 8

    const int nwg = gridDim.x;
    const int cpx = nwg >> 3;
    const int id  = blockIdx.x;
    const int sw  = (id & 7) * cpx + (id >> 3);
    const int bx = sw % nbx, by = sw / nbx;
    const int m0 = by * 128, n0 = bx * 128;

    const int tid  = threadIdx.x;
    const int lane = tid & 63;
    const int wv   = tid >> 6;
    const int l4   = lane >> 4, l16 = lane & 15;
    const int wm   = wv >> 1,  wn  = wv & 1;

    const int r0  = tid >> 2;
    const int c0  = (tid & 3) * 16;
    const int ch0 = c0 >> 3;

    f32x4 acc[4][4];
#pragma unroll
    for (int i = 0; i < 4; ++i)
#pragma unroll
        for (int j = 0; j < 4; ++j) acc[i][j] = 0.f;

    short8 stgA[4], stgB[4];
#pragma unroll
    for (int it = 0; it < 2; ++it) {
        const ushort_t* ahp = Ah + (size_t)(m0 + r0 + 64 * it) * CC + c0;
        stgA[2 * it]     = *(const short8*)(ahp);
        stgA[2 * it + 1] = *(const short8*)(ahp + 8);
        const ushort_t* bhp = Bh + (size_t)(n0 + r0 + 64 * it) * K + c0;
        stgB[2 * it]     = *(const short8*)(bhp);
        stgB[2 * it + 1] = *(const short8*)(bhp + 8);
    }

    for (int kt = 0; kt < K; kt += 64) {
        __syncthreads();
#pragma unroll
        for (int it = 0; it < 2; ++it) {
            const int row  = r0 + 64 * it;
            const int sA   = row & 7;
            const int base = row * 64;
            const int cA = ((ch0) ^ sA) * 8, cB = ((ch0 + 1) ^ sA) * 8;
            *(short8*)&sAh[base + cA] = stgA[2 * it];
            *(short8*)&sAh[base + cB] = stgA[2 * it + 1];
            *(short8*)&sBh[base + cA] = stgB[2 * it];
            *(short8*)&sBh[base + cB] = stgB[2 * it + 1];
        }
        __syncthreads();

        if (kt + 64 < K) { // prefetch next K-tile
#pragma unroll
            for (int it = 0; it < 2; ++it) {
                const ushort_t* ahp = Ah + (size_t)(m0 + r0 + 64 * it) * CC + kt + 64 + c0;
                stgA[2 * it]     = *(const short8*)(ahp);
                stgA[2 * it + 1] = *(const short8*)(ahp + 8);
                const ushort_t* bhp = Bh + (size_t)(n0 + r0 + 64 * it) * K + kt + 64 + c0;
                stgB[2 * it]     = *(const short8*)(bhp);
                stgB[2 * it + 1] = *(const short8*)(bhp + 8);
            }
        }

#pragma unroll
        for (int ks = 0; ks < 2; ++ks) {
            const int chf = (((ks << 2) | l4) ^ (l16 & 7)) * 8;
            short8 fbh[4];
#pragma unroll
            for (int j = 0; j < 4; ++j) {
                const int idx = (64 * wn + 16 * j + l16) * 64 + chf;
                fbh[j] = *(const short8*)&sBh[idx];
            }
#pragma unroll
            for (int i = 0; i < 4; ++i) {
                const int idx = (64 * wm + 16 * i + l16) * 64 + chf;
                short8 fah = *(const short8*)&sAh[idx];
#pragma unroll
                for (int j = 0; j < 4; ++j)
                    acc[i][j] = MFMA_BF16(fah, fbh[j], acc[i][j]);
            }
        }
    }

    float bv[4];
#pragma unroll
    for (int j = 0; j < 4; ++j) bv[j] = bias[n0 + 64 * wn + 16 * j + l16];
#pragma unroll
    for (int i = 0; i < 4; ++i)
#pragma unroll
    for (int r = 0; r < 4; ++r) {
        const int row = m0 + 64 * wm + 16 * i + 4 * l4 + r;
        float* cp = Cg + (size_t)row * CC + n0 + 64 * wn + l16;
#pragma unroll
        for (int j = 0; j < 4; ++j) cp[16 * j] = acc[i][j][r] + bv[j];
    }
}

// ---------------------------------------------------------------------------
// Flash attention v11 (round-18 proven best, 87.4 us): QF=4 (64 q-rows per
// wave), K/V LDS reads, staging and barriers amortized over 2x q-rows vs the
// 32-row version. Fixed-shift exp2 softmax (rmsnorm bounds |S| <= 11.63
// log2-units; constant shift cancels in O/l), KVBLK=64, zero bank conflicts,
// row-sum l via MFMA(P, ones). 512 blocks = 2/CU.
// ---------------------------------------------------------------------------
__global__ __launch_bounds__(256, 2)
void flash11(const ushort_t* __restrict__ Qbh,
             const ushort_t* __restrict__ Kh,
             const ushort_t* __restrict__ Vth,
             ushort_t* __restrict__ Hb)
{
    __shared__ ushort_t sKh[4096], sVh[4096]; // 16 KB
    __shared__ ushort_t sP[4][64 * 68];       // 34 KB

    const int i    = blockIdx.x;          // 0..511
    const int xcd  = i & 7;
    const int slot = i >> 3;              // 0..63
    const int qt   = slot & 7;            // 8 q-tiles of 256 rows
    const int bh   = ((slot >> 3) << 3) | xcd;
    const int b    = bh >> 4, h = bh & 15;

    const int tid  = threadIdx.x;
    const int lane = tid & 63;
    const int wv   = tid >> 6;
    const int l4   = lane >> 4, l16 = lane & 15;

    // ---- Q fragments: 4 q-frags per wave (64 rows), pre-scaled bf16
    short8 qh[4][2];
    const int qr0 = qt * 256 + wv * 64;
#pragma unroll
    for (int qf = 0; qf < 4; ++qf)
#pragma unroll
    for (int sl = 0; sl < 2; ++sl)
        qh[qf][sl] = *(const short8*)(Qbh + (size_t)(b * LL + qr0 + qf * 16 + l16) * CC
                                      + h * DD + sl * 32 + l4 * 8);

    // bf16 1.0 vector for the MFMA row-sum
    short8 ones;
#pragma unroll
    for (int j = 0; j < 8; ++j) ones[j] = (short)0x3F80;

    f32x4 O[4][4];
    f32x4 acc_l[4];   // row-sum of P, layout q = 4*l4 + r (same as O rows)
#pragma unroll
    for (int qf = 0; qf < 4; ++qf) {
        acc_l[qf] = 0.f;
#pragma unroll
        for (int t = 0; t < 4; ++t) O[qf][t] = 0.f;
    }

    const int r_ = tid >> 2;          // staging row 0..63
    const int c2 = (tid & 3) * 2;     // chunk pair

    short8 stg[4];
    {
        const size_t kgb = ((size_t)bh * LL + r_) * DD + c2 * 8;
        const size_t vgb = ((size_t)bh * DD + r_) * LL + c2 * 8;
        stg[0] = *(const short8*)&Kh[kgb];  stg[1] = *(const short8*)&Kh[kgb + 8];
        stg[2] = *(const short8*)&Vth[vgb]; stg[3] = *(const short8*)&Vth[vgb + 8];
    }

    for (int kt = 0; kt < LL / 64; ++kt) {
        __syncthreads(); // previous tile fully consumed
        {
            const int wr = r_ * 64, s = r_ & 7;
            const int cA = ((c2) ^ s) * 8, cB = ((c2 + 1) ^ s) * 8;
            *(short8*)&sKh[wr + cA] = stg[0];
            *(short8*)&sKh[wr + cB] = stg[1];
            *(short8*)&sVh[wr + cA] = stg[2];
            *(short8*)&sVh[wr + cB] = stg[3];
        }
        __syncthreads();
        if (kt + 1 < LL / 64) { // prefetch next tile into regs
            const size_t kgb = ((size_t)bh * LL + (kt + 1) * 64 + r_) * DD + c2 * 8;
            const size_t vgb = ((size_t)bh * DD + r_) * LL + (kt + 1) * 64 + c2 * 8;
            stg[0] = *(const short8*)&Kh[kgb];  stg[1] = *(const short8*)&Kh[kgb + 8];
            stg[2] = *(const short8*)&Vth[vgb]; stg[3] = *(const short8*)&Vth[vgb + 8];
        }

        // ---- S^T = K Q : rows k (16t + 4*l4 + r), cols q (l16); log2 units
        f32x4 S[4][4];
#pragma unroll
        for (int qf = 0; qf < 4; ++qf)
#pragma unroll
        for (int t = 0; t < 4; ++t) S[qf][t] = 0.f;

        __builtin_amdgcn_s_setprio(1);
#pragma unroll
        for (int t = 0; t < 4; ++t) {
            const int row = 16 * t + l16;
            const int swr = row & 7;
#pragma unroll
            for (int sl = 0; sl < 2; ++sl) {
                const int idx = row * 64 + (((sl << 2) | l4) ^ swr) * 8;
                short8 kh8 = *(const short8*)&sKh[idx];
#pragma unroll
                for (int qf = 0; qf < 4; ++qf)
                    S[qf][t] = MFMA_BF16(kh8, qh[qf][sl], S[qf][t]);
            }
        }
        __builtin_amdgcn_s_setprio(0);

        // ---- P = exp2(S) (fixed-shift softmax; constant cancels in O/l)
#pragma unroll
        for (int qf = 0; qf < 4; ++qf)
#pragma unroll
        for (int t = 0; t < 4; ++t)
#pragma unroll
            for (int r = 0; r < 4; ++r)
                S[qf][t][r] = fast_exp2(S[qf][t][r]);

        // ---- P -> per-wave LDS (bf16, half-up + v_perm pack), b64 writes
#pragma unroll
        for (int qf = 0; qf < 4; ++qf)
#pragma unroll
        for (int t = 0; t < 4; ++t) {
            unsigned lo = pack_bf2(S[qf][t][0], S[qf][t][1]);
            unsigned hi = pack_bf2(S[qf][t][2], S[qf][t][3]);
            const int widx = (qf * 16 + l16) * 68 + 16 * t + 4 * l4;
            *(u64_t*)&sP[wv][widx] = (u64_t)lo | ((u64_t)hi << 32);
        }
        asm volatile("s_waitcnt lgkmcnt(0)" ::: "memory");
        __builtin_amdgcn_sched_barrier(0);

        // ---- P A-fragments: row q = l16, k = sl*32 + 8*l4 + j
        short8 pa[4][2];
#pragma unroll
        for (int qf = 0; qf < 4; ++qf)
#pragma unroll
        for (int sl = 0; sl < 2; ++sl) {
            const int ridx = (qf * 16 + l16) * 68 + sl * 32 + 8 * l4;
            union { u64_t q[2]; short8 s8; } u;
            u.q[0] = *(const u64_t*)&sP[wv][ridx];
            u.q[1] = *(const u64_t*)&sP[wv][ridx + 4];
            pa[qf][sl] = u.s8;
        }

        // ---- O += P V ; acc_l += P . ones (row-sum in O's layout)
        __builtin_amdgcn_s_setprio(1);
#pragma unroll
        for (int qf = 0; qf < 4; ++qf) {
            acc_l[qf] = MFMA_BF16(pa[qf][0], ones, acc_l[qf]);
            acc_l[qf] = MFMA_BF16(pa[qf][1], ones, acc_l[qf]);
        }
#pragma unroll
        for (int dt = 0; dt < 4; ++dt) {
            const int row = 16 * dt + l16;
            const int swr = row & 7;
#pragma unroll
            for (int sl = 0; sl < 2; ++sl) {
                const int idx = row * 64 + (((sl << 2) | l4) ^ swr) * 8;
                short8 vh8 = *(const short8*)&sVh[idx];
#pragma unroll
                for (int qf = 0; qf < 4; ++qf)
                    O[qf][dt] = MFMA_BF16(pa[qf][sl], vh8, O[qf][dt]);
            }
        }
        __builtin_amdgcn_s_setprio(0);
    }

    // ---- epilogue: h = O / l -> bf16 Hb rows (l is lane-local)
#pragma unroll
    for (int qf = 0; qf < 4; ++qf) {
        f32x4 iv;
#pragma unroll
        for (int r = 0; r < 4; ++r) iv[r] = 1.0f / acc_l[qf][r];
#pragma unroll
        for (int r = 0; r < 4; ++r) {
            const int q = qr0 + qf * 16 + 4 * l4 + r;
            ushort_t* op = Hb + (size_t)(b * LL + q) * CC + h * DD + l16;
#pragma unroll
            for (int dt = 0; dt < 4; ++dt)
                op[16 * dt] = f2bf(O[qf][dt][r] * iv[r]);
        }
    }
}

// ---------------------------------------------------------------------------
// Legacy fp32 fallback kernels (only if ws_size is too small; never expected)
// ---------------------------------------------------------------------------
#define Bb 128
#define Bn 128
#define BKG 8

__global__ __launch_bounds__(256)
void gemm_bias(const float* __restrict__ A, const float* __restrict__ B,
               const float* __restrict__ bias, float* __restrict__ C,
               int M, int N, int K, int lda, int ldb, int ldc)
{
    __shared__ float As[BKG][Bb];
    __shared__ float Bs[BKG][Bn];

    const int tid = threadIdx.x;
    const int m0 = blockIdx.y * Bb;
    const int n0 = blockIdx.x * Bn;
    const int ty = tid >> 4, tx = tid & 15;
    const int arow = tid >> 1, acol = (tid & 1) * 4;
    const int brow = tid >> 5, bcol = (tid & 31) * 4;

    const float* Ap = A + (size_t)(m0 + arow) * lda + acol;
    const float* Bp = B + (size_t)brow * ldb + n0 + bcol;

    float acc[8][8];
#pragma unroll
    for (int i = 0; i < 8; ++i)
#pragma unroll
        for (int j = 0; j < 8; ++j) acc[i][j] = 0.f;

    for (int k0 = 0; k0 < K; k0 += BKG) {
        float4 av = *(const float4*)(Ap + k0);
        float4 bv = *(const float4*)(Bp + (size_t)k0 * ldb);
        __syncthreads();
        As[acol + 0][arow] = av.x;
        As[acol + 1][arow] = av.y;
        As[acol + 2][arow] = av.z;
        As[acol + 3][arow] = av.w;
        *(float4*)&Bs[brow][bcol] = bv;
        __syncthreads();
#pragma unroll
        for (int kk = 0; kk < BKG; ++kk) {
            float a[8], bvv[8];
            *(float4*)&a[0] = *(const float4*)&As[kk][ty * 4];
            *(float4*)&a[4] = *(const float4*)&As[kk][64 + ty * 4];
            *(float4*)&bvv[0] = *(const float4*)&Bs[kk][tx * 4];
            *(float4*)&bvv[4] = *(const float4*)&Bs[kk][64 + tx * 4];
#pragma unroll
            for (int i = 0; i < 8; ++i)
#pragma unroll
                for (int j = 0; j < 8; ++j)
                    acc[i][j] = fmaf(a[i], bvv[j], acc[i][j]);
        }
    }
#pragma unroll
    for (int ih = 0; ih < 2; ++ih)
#pragma unroll
    for (int i = 0; i < 4; ++i) {
        const int m = m0 + ih * 64 + ty * 4 + i;
#pragma unroll
        for (int jh = 0; jh < 2; ++jh) {
            const int n = n0 + jh * 64 + tx * 4;
            float4 o;
            o.x = acc[ih*4+i][jh*4+0] + bias[n+0];
            o.y = acc[ih*4+i][jh*4+1] + bias[n+1];
            o.z = acc[ih*4+i][jh*4+2] + bias[n+2];
            o.w = acc[ih*4+i][jh*4+3] + bias[n+3];
            *(float4*)(C + (size_t)m * ldc + n) = o;
        }
    }
}

__global__ __launch_bounds__(256)
void rmsnorm_qk(float* __restrict__ qkv,
                const float* __restrict__ gq, const float* __restrict__ gk)
{
    const int gt    = blockIdx.x * 256 + threadIdx.x;
    const int lane  = gt & 63;
    const int wave  = gt >> 6;
    const int which = wave & 1;
    const int h     = (wave >> 1) & (HH - 1);
    const int bl    = wave >> 5;

    float* p = qkv + (size_t)bl * (3 * CC) + which * CC + h * DD + lane;
    float v = *p;
    float ss = v * v;
#pragma unroll
    for (int off = 32; off; off >>= 1) ss += __shfl_xor(ss, off);
    float nrm = fmaxf(sqrtf(ss), 1e-12f);
    const float* g = which ? gk : gq;
    *p = v * (8.0f / nrm) * g[h * DD + lane];
}

__global__ __launch_bounds__(256)
void flash_fp32(float* __restrict__ qkv)
{
    const int qt = blockIdx.x, hh = blockIdx.y, bb = blockIdx.z;

    __shared__ float Qt[DD][64];
    __shared__ float Kt[DD][64];
    __shared__ float Vs[64][DD];
    __shared__ float Ps[64][64 + 4];

    const int tid = threadIdx.x;
    const int ty = tid >> 4, tx = tid & 15;
    const size_t rs_ = 3 * CC;
    const float* qbase = qkv + ((size_t)bb * LL + (size_t)qt * 64) * rs_ + hh * DD;
    const float* kbase = qkv + (size_t)bb * LL * rs_ + CC + hh * DD;
    const float* vbase = kbase + CC;

    {
        const int r = tid >> 2, c0 = (tid & 3) * 16;
#pragma unroll
        for (int u = 0; u < 4; ++u) {
            float4 v = *(const float4*)(qbase + (size_t)r * rs_ + c0 + u * 4);
            Qt[c0 + u*4 + 0][r] = v.x; Qt[c0 + u*4 + 1][r] = v.y;
            Qt[c0 + u*4 + 2][r] = v.z; Qt[c0 + u*4 + 3][r] = v.w;
        }
    }

    float mrow[4], lrow[4], O[4][4];
#pragma unroll
    for (int i = 0; i < 4; ++i) {
        mrow[i] = -INFINITY; lrow[i] = 0.f;
#pragma unroll
        for (int j = 0; j < 4; ++j) O[i][j] = 0.f;
    }

    for (int kt = 0; kt < LL / 64; ++kt) {
        __syncthreads();
        {
            const int r = tid >> 2, c0 = (tid & 3) * 16;
            const float* kr = kbase + ((size_t)kt * 64 + r) * rs_;
            const float* vr = vbase + ((size_t)kt * 64 + r) * rs_;
#pragma unroll
            for (int u = 0; u < 4; ++u) {
                float4 kv = *(const float4*)(kr + c0 + u * 4);
                Kt[c0 + u*4 + 0][r] = kv.x; Kt[c0 + u*4 + 1][r] = kv.y;
                Kt[c0 + u*4 + 2][r] = kv.z; Kt[c0 + u*4 + 3][r] = kv.w;
                *(float4*)&Vs[r][c0 + u*4] = *(const float4*)(vr + c0 + u * 4);
            }
        }
        __syncthreads();

        float S[4][4];
#pragma unroll
        for (int i = 0; i < 4; ++i)
#pragma unroll
            for (int j = 0; j < 4; ++j) S[i][j] = 0.f;
#pragma unroll 8
        for (int d = 0; d < DD; ++d) {
            float a[4], b[4];
            *(float4*)a = *(const float4*)&Qt[d][ty * 4];
            *(float4*)b = *(const float4*)&Kt[d][tx * 4];
#pragma unroll
            for (int i = 0; i < 4; ++i)
#pragma unroll
                for (int j = 0; j < 4; ++j) S[i][j] = fmaf(a[i], b[j], S[i][j]);
        }
#pragma unroll
        for (int i = 0; i < 4; ++i) {
#pragma unroll
            for (int j = 0; j < 4; ++j) S[i][j] *= 0.125f;
            float pm = fmaxf(fmaxf(S[i][0], S[i][1]), fmaxf(S[i][2], S[i][3]));
#pragma unroll
            for (int off = 1; off < 16; off <<= 1) pm = fmaxf(pm, __shfl_xor(pm, off));
            const float mnew = fmaxf(mrow[i], pm);
            const float corr = __expf(mrow[i] - mnew);
            float rsum = 0.f;
#pragma unroll
            for (int j = 0; j < 4; ++j) { S[i][j] = __expf(S[i][j] - mnew); rsum += S[i][j]; }
#pragma unroll
            for (int off = 1; off < 16; off <<= 1) rsum += __shfl_xor(rsum, off);
            mrow[i] = mnew;
            lrow[i] = lrow[i] * corr + rsum;
#pragma unroll
            for (int j = 0; j < 4; ++j) O[i][j] *= corr;
        }
#pragma unroll
        for (int i = 0; i < 4; ++i)
            *(float4*)&Ps[ty * 4 + i][tx * 4] = *(float4*)&S[i][0];
        __syncthreads();
#pragma unroll 4
        for (int k = 0; k < 64; k += 4) {
            float a[4][4];
#pragma unroll
            for (int i = 0; i < 4; ++i)
                *(float4*)&a[i][0] = *(const float4*)&Ps[ty * 4 + i][k];
#pragma unroll
            for (int kk = 0; kk < 4; ++kk) {
                float bv[4];
                *(float4*)bv = *(const float4*)&Vs[k + kk][tx * 4];
#pragma unroll
                for (int i = 0; i < 4; ++i)
#pragma unroll
                    for (int j = 0; j < 4; ++j)
                        O[i][j] = fmaf(a[i][kk], bv[j], O[i][j]);
            }
        }
    }

    float* obase = qkv + ((size_t)bb * LL + (size_t)qt * 64) * rs_ + hh * DD;
#pragma unroll
    for (int i = 0; i < 4; ++i) {
        const float inv = 1.f / lrow[i];
        float4 o;
        o.x = O[i][0] * inv; o.y = O[i][1] * inv;
        o.z = O[i][2] * inv; o.w = O[i][3] * inv;
        *(float4*)(obase + (size_t)(ty * 4 + i) * rs_ + tx * 4) = o;
    }
}

// ---------------------------------------------------------------------------
extern "C" void kernel_launch(void* const* d_in, const int* in_sizes, int n_in,
                              void* d_out, int out_size, void* d_ws, size_t ws_size,
                              hipStream_t stream)
{
    const float* x    = (const float*)d_in[0];
    const float* Wqkv = (const float*)d_in[1];
    const float* bqkv = (const float*)d_in[2];
    const float* gq   = (const float*)d_in[3];
    const float* gk   = (const float*)d_in[4];
    const float* Wout = (const float*)d_in[5];
    const float* bout = (const float*)d_in[6];
    float* out = (float*)d_out;

    const size_t NEED = 92274688ull; // 88 MiB (proven available)

    if (ws_size >= NEED) {
        char* wsb = (char*)d_ws;
        ushort_t* Qbh = (ushort_t*)(wsb);                 // 16 MiB
        ushort_t* Kh  = (ushort_t*)(wsb + 16777216);      // 16 MiB
        ushort_t* Vth = (ushort_t*)(wsb + 33554432);      // 16 MiB
        ushort_t* Hb  = (ushort_t*)(wsb + 50331648);      // 16 MiB
        ushort_t* wqh = (ushort_t*)(wsb + 67108864);      // 6 MiB
        ushort_t* woh = (ushort_t*)(wsb + 73400320);      // 2 MiB
        ushort_t* xh  = (ushort_t*)(wsb + 75497472);      // 16 MiB

        // one fused prep launch: x->bf16 (4096 blocks) + WqkvT (768) + WoutT (256)
        prep_all<<<dim3(4096 + 768 + 256), 256, 0, stream>>>(
            x, xh, Wqkv, wqh, Wout, woh);

        gemm_qkv<<<dim3(24 * 64), 256, 0, stream>>>(
            xh, wqh, bqkv, gq, gk, Qbh, Kh, Vth);

        flash11<<<dim3(512), 256, 0, stream>>>(Qbh, Kh, Vth, Hb);

        gemm_out1<<<dim3(8 * 64), 256, 0, stream>>>(Hb, woh, bout, out);
    } else {
        // legacy fp32 path
        float* qkv = (float*)d_ws;
        gemm_bias<<<dim3((3 * CC) / Bn, MM / Bb), 256, 0, stream>>>(
            x, Wqkv, bqkv, qkv, MM, 3 * CC, CC, CC, 3 * CC, 3 * CC);
        rmsnorm_qk<<<dim3((MM * HH * 2 * 64) / 256), 256, 0, stream>>>(qkv, gq, gk);
        flash_fp32<<<dim3(LL / 64, HH, BB), 256, 0, stream>>>(qkv);
        gemm_bias<<<dim3(CC / Bn, MM / Bb), 256, 0, stream>>>(
            qkv, Wout, bout, out, MM, CC, CC, 3 * CC, CC, CC);
    }
}